// Round 6
// baseline (1402.987 us; speedup 1.0000x reference)
//
#include <hip/hip_runtime.h>
#include <math.h>

// Problem constants
#define NROWS 32768   // B*H*W
#define KCB   1024    // num embeddings
#define DDIM  256     // embedding dim

// Output offsets (in floats)
#define O_LOSS 0
#define O_Q    1
#define O_PERP 8388609
#define O_ENC  8388610
#define O_NCNT 41943042
#define O_EMAW 41944066
#define O_EMB  42206210

// E-region scratch layout (floats rel. outE; region = 33,554,432 floats exactly)
#define E_XS3   0          // XS3 bf16 [32768][768] (hi|mid|lo) = 12,582,912 floats
#define E_SOFTT 12582912   // softT bf16 [1024][32768] = 16,777,216 floats
#define E_XBF   29360128   // xbf bf16 [32][256][1024] = 4,194,304 floats  (ends 33,554,432)

// Workspace offsets (floats)
#define W_WSQ  0        // 1024
#define W_XSQ  1024     // 32768
#define W_IDX  33792    // 32768 (int)
#define W_COL  66560    // 1024
#define W_HCNT 67584    // 1024
#define W_BENT 68608    // 512
#define W_NCNT 69120    // 1024
#define W_T2V  70144    // 65536
#define W_T2I  135680   // 65536 (int)
#define W_WB   201216   // 1024*768 ushorts = 393216 floats
// total 594,432 floats = 2.38 MB

typedef __attribute__((ext_vector_type(8))) short bf16x8;
typedef __attribute__((ext_vector_type(4))) float f32x4;

#define GLOAD_LDS16(g, l) __builtin_amdgcn_global_load_lds( \
    (const __attribute__((address_space(1))) unsigned int*)(g), \
    (__attribute__((address_space(3))) unsigned int*)(l), 16, 0, 0)

__device__ __forceinline__ float wred_sum(float v) {
#pragma unroll
  for (int off = 32; off > 0; off >>= 1) v += __shfl_xor(v, off);
  return v;
}
__device__ __forceinline__ ushort f2bf(float f) {
  union { float f; unsigned u; } c; c.f = f;
  unsigned u = c.u;
  return (ushort)((u + 0x7fffu + ((u >> 16) & 1u)) >> 16);  // RNE
}
__device__ __forceinline__ float bf2f(ushort h) {
  union { unsigned u; float f; } c; c.u = ((unsigned)h) << 16;
  return c.f;
}

// ---------------- init: zero hcnt ----------------
__global__ void k_init(float* __restrict__ hcnt) {
  int i = blockIdx.x * 256 + threadIdx.x;
  if (i < 1024) hcnt[i] = 0.f;
}

// ---------------- w -> wsq + WB [k][768] = [w_hi | w_hi | w_mid] ----------------
__global__ void k_wsplit(const float* __restrict__ w, float* __restrict__ wsq,
                         ushort* __restrict__ WB) {
  int t = threadIdx.x;
  int lane = t & 63, wv = t >> 6;
  int k = blockIdx.x * 4 + wv;
  int d0 = lane * 4;
  float4 v = *(const float4*)&w[(size_t)k * DDIM + d0];
  float s = v.x * v.x + v.y * v.y + v.z * v.z + v.w * v.w;
  s = wred_sum(s);
  if (lane == 0) wsq[k] = s;
  float vv[4] = {v.x, v.y, v.z, v.w};
  union { ushort u[4]; uint2 q; } hh, mm;
#pragma unroll
  for (int q = 0; q < 4; ++q) {
    ushort h = f2bf(vv[q]);
    float r = vv[q] - bf2f(h);
    hh.u[q] = h;
    mm.u[q] = f2bf(r);
  }
  ushort* row = WB + (size_t)k * 768;
  *(uint2*)&row[d0] = hh.q;
  *(uint2*)&row[256 + d0] = hh.q;
  *(uint2*)&row[512 + d0] = mm.q;
}

// ---------------- x -> XS3 (3-way bf16 split, row-major) + xbf (d-major bf16) + xsq ----------------
__global__ __launch_bounds__(256) void k_xsplit(const float* __restrict__ x,
                                                ushort* __restrict__ XS3,
                                                ushort* __restrict__ xbf,
                                                float* __restrict__ xsq) {
  __shared__ __align__(16) ushort sl[32 * 776];
  __shared__ float sq[32 * 9];
  int t = threadIdx.x;
  int b = blockIdx.x >> 5, mt = blockIdx.x & 31;
  int m0 = mt * 32, mloc = t & 31, dgrp = t >> 5;
  const float* xb = x + (size_t)b * DDIM * 1024 + m0 + mloc;
  float s = 0.f;
#pragma unroll
  for (int jj = 0; jj < 8; ++jj) {
    int d0 = dgrp * 32 + jj * 4;
    float vv[4];
#pragma unroll
    for (int q = 0; q < 4; ++q) vv[q] = xb[(size_t)(d0 + q) * 1024];
    union { ushort u[4]; uint2 q; } hh, mi, lo;
#pragma unroll
    for (int q = 0; q < 4; ++q) {
      float v = vv[q];
      ushort h = f2bf(v);
      float r1 = v - bf2f(h);
      ushort m_ = f2bf(r1);
      float r2 = r1 - bf2f(m_);
      hh.u[q] = h; mi.u[q] = m_; lo.u[q] = f2bf(r2);
      s = fmaf(v, v, s);
    }
    int base = mloc * 776;
    *(uint2*)&sl[base + d0] = hh.q;
    *(uint2*)&sl[base + 256 + d0] = mi.q;
    *(uint2*)&sl[base + 512 + d0] = lo.q;
#pragma unroll
    for (int q = 0; q < 4; ++q)
      xbf[(size_t)(b * DDIM + d0 + q) * 1024 + m0 + mloc] = hh.u[q];
  }
  sq[mloc * 9 + dgrp] = s;
  __syncthreads();
  if (t < 32) {
    float ss = 0.f;
#pragma unroll
    for (int gq = 0; gq < 8; ++gq) ss += sq[t * 9 + gq];
    xsq[b * 1024 + m0 + t] = ss;
  }
  ushort* dst = XS3 + (size_t)(b * 1024 + m0) * 768;
#pragma unroll
  for (int p = 0; p < 12; ++p) {
    int idx = p * 256 + t;          // 0..3071 ; 96 x 16B chunks per row
    int row = idx / 96;
    int co = idx - row * 96;
    *(uint4*)&dst[(size_t)row * 768 + co * 8] = *(uint4*)&sl[row * 776 + co * 8];
  }
}

// ---------------- fused GEMM1(MFMA split-bf16) + softmax + top2 + entropy + softT ----------------
// tile 64n x 1024k; 16 single-buffered async K-steps of 32 (B-reuse: w_hi used for
// x_hi AND x_mid); 512 threads = 8 waves (2n x 4k).
// LDS: shm = 73728 B  (B tile [0,65536) | A tile [65536,73728))
// Epilogue aliases shm: wsql@[0,4096) t2v@[4096,6144) t2i@[6144,8192)
//   redf@[8192,9216) tsl@[0,36864) (lifetimes ordered by barriers).
// Total __shared__ ~74 KB -> 2 blocks/CU (16 waves) for latency hiding.
__global__ __launch_bounds__(512, 4) void k_score(const ushort* __restrict__ XS3,
                                                  const ushort* __restrict__ WB,
                                                  const float* __restrict__ G,
                                                  const float* __restrict__ wsq,
                                                  const float* __restrict__ xsq,
                                                  ushort* __restrict__ softT,
                                                  float* __restrict__ bent,
                                                  float* __restrict__ t2vg,
                                                  int* __restrict__ t2ig) {
  __shared__ __align__(16) ushort shm[36864];  // 73728 B
  __shared__ float sxl[64];
  __shared__ float bacc[8];
  ushort* tsl = shm;
  char* shmB = (char*)shm;
  float* wsqlp = (float*)shm;
  float* t2vp = (float*)(shmB + 4096);
  int*   t2ip = (int*)(shmB + 6144);
  float* redfp = (float*)(shmB + 8192);

  int t = threadIdx.x;
  int n0 = blockIdx.x * 64;
  int l = t & 63, wid = t >> 6;
  int ng = wid >> 2, kg = wid & 3;
  int c = l & 15, g = l >> 4;

  if (t < 64) sxl[t] = xsq[n0 + t];
  __syncthreads();

  f32x4 zero = {0.f, 0.f, 0.f, 0.f};
  f32x4 acc[2][16];
#pragma unroll
  for (int i = 0; i < 2; ++i)
#pragma unroll
    for (int j = 0; j < 16; ++j) acc[i][j] = zero;

  const char* WBb = (const char*)WB;
  const char* XSb = (const char*)XS3;
  int rsub = l & 15, gsub = l >> 4;  // lane -> (row-in-subtile, granule)
  const ushort* Bb = shm;
  const ushort* Ab = shm + 32768;  // byte 65536

  for (int s = 0; s < 16; ++s) {
    // ---- DMA issue for step s (9 wave-loads per wave) ----
    {
      int isHi = (s < 8);
      int koffB = isHi ? s * 32 : 512 + (s - 8) * 32;
#pragma unroll
      for (int p = 0; p < 8; ++p) {
        int st = wid * 8 + p;
        int row = st * 16 + rsub;
        GLOAD_LDS16(WBb + (size_t)row * 1536 + koffB * 2 + gsub * 16,
                    shmB + st * 1024);
      }
      int slab = isHi ? (wid >> 2) : 0;
      int sub = wid & 3;
      int aoff = isHi ? (slab ? 256 + s * 32 : s * 32) : (s - 8) * 32;
      int arow = n0 + sub * 16 + rsub;
      GLOAD_LDS16(XSb + (size_t)arow * 1536 + aoff * 2 + gsub * 16,
                  shmB + 65536 + slab * 4096 + sub * 1024);
    }
    asm volatile("s_waitcnt vmcnt(0)" ::: "memory");
    __builtin_amdgcn_s_barrier();
    __builtin_amdgcn_sched_barrier(0);

    int fo = g * 128 + c * 8;
    bf16x8 a0h = *(const bf16x8*)&Ab[ng * 1024 + fo];
    bf16x8 a1h = *(const bf16x8*)&Ab[ng * 1024 + 512 + fo];
    if (s < 8) {
      bf16x8 a0m = *(const bf16x8*)&Ab[2048 + ng * 1024 + fo];
      bf16x8 a1m = *(const bf16x8*)&Ab[2048 + ng * 1024 + 512 + fo];
#pragma unroll
      for (int j = 0; j < 16; ++j) {
        bf16x8 bF = *(const bf16x8*)&Bb[(kg * 16 + j) * 512 + fo];
        acc[0][j] = __builtin_amdgcn_mfma_f32_16x16x32_bf16(a0h, bF, acc[0][j], 0, 0, 0);
        acc[1][j] = __builtin_amdgcn_mfma_f32_16x16x32_bf16(a1h, bF, acc[1][j], 0, 0, 0);
        acc[0][j] = __builtin_amdgcn_mfma_f32_16x16x32_bf16(a0m, bF, acc[0][j], 0, 0, 0);
        acc[1][j] = __builtin_amdgcn_mfma_f32_16x16x32_bf16(a1m, bF, acc[1][j], 0, 0, 0);
      }
    } else {
#pragma unroll
      for (int j = 0; j < 16; ++j) {
        bf16x8 bF = *(const bf16x8*)&Bb[(kg * 16 + j) * 512 + fo];
        acc[0][j] = __builtin_amdgcn_mfma_f32_16x16x32_bf16(a0h, bF, acc[0][j], 0, 0, 0);
        acc[1][j] = __builtin_amdgcn_mfma_f32_16x16x32_bf16(a1h, bF, acc[1][j], 0, 0, 0);
      }
    }
    __syncthreads();  // all waves done reading before next step's DMA overwrite
  }

  // ===== epilogue (math identical to verified round-4/5; arrays aliased in shm) =====
  // fill wsql (B region is dead now)
  wsqlp[t] = wsq[t];
  wsqlp[t + 512] = wsq[t + 512];
  __syncthreads();

  // nd = 2*s - xs - wq  (negative distance)
#pragma unroll
  for (int i = 0; i < 2; ++i)
#pragma unroll
    for (int j = 0; j < 16; ++j) {
      float wq = wsqlp[kg * 256 + j * 16 + c];
#pragma unroll
      for (int r = 0; r < 4; ++r) {
        float xsv = sxl[ng * 32 + i * 16 + g * 4 + r];
        acc[i][j][r] = fmaf(2.f, acc[i][j][r], -(xsv + wq));
      }
    }

  // top-2 of nd+gumbel per row
#pragma unroll
  for (int i = 0; i < 2; ++i)
#pragma unroll
    for (int r = 0; r < 4; ++r) {
      int rowloc = ng * 32 + i * 16 + g * 4 + r;
      const float* Grow = G + (((size_t)(n0 + rowloc)) << 10) + kg * 256 + c;
      float v1 = -3.0e38f, v2 = -3.0e38f;
      int i1 = 0x7fffffff, i2 = 0x7fffffff;
#pragma unroll
      for (int j = 0; j < 16; ++j) {
        float sc = acc[i][j][r] + Grow[j * 16];
        int kk = kg * 256 + j * 16 + c;
        if (sc > v1 || (sc == v1 && kk < i1)) {
          v2 = v1; i2 = i1; v1 = sc; i1 = kk;
        } else if (sc > v2 || (sc == v2 && kk < i2)) {
          v2 = sc; i2 = kk;
        }
      }
#pragma unroll
      for (int off = 1; off < 16; off <<= 1) {
        float ov1 = __shfl_xor(v1, off), ov2 = __shfl_xor(v2, off);
        int oi1 = __shfl_xor(i1, off), oi2 = __shfl_xor(i2, off);
        bool fB = (ov1 > v1) || (ov1 == v1 && oi1 < i1);
        float nv1 = fB ? ov1 : v1; int ni1 = fB ? oi1 : i1;
        float ca = fB ? v1 : ov1;  int cia = fB ? i1 : oi1;
        float cb = fB ? ov2 : v2;  int cib = fB ? oi2 : i2;
        bool sB = (cb > ca) || (cb == ca && cib < cia);
        v1 = nv1; i1 = ni1;
        v2 = sB ? cb : ca; i2 = sB ? cib : cia;
      }
      if (c == 0) {
        t2vp[kg * 128 + rowloc * 2 + 0] = v1; t2vp[kg * 128 + rowloc * 2 + 1] = v2;
        t2ip[kg * 128 + rowloc * 2 + 0] = i1; t2ip[kg * 128 + rowloc * 2 + 1] = i2;
      }
    }
  __syncthreads();  // B0
  if (t < 64) {
    float v1 = -3.0e38f, v2 = -3.0e38f;
    int i1 = 0x7fffffff, i2 = 0x7fffffff;
#pragma unroll
    for (int q = 0; q < 4; ++q)
#pragma unroll
      for (int u = 0; u < 2; ++u) {
        float sc = t2vp[q * 128 + t * 2 + u];
        int kk = t2ip[q * 128 + t * 2 + u];
        if (sc > v1 || (sc == v1 && kk < i1)) {
          v2 = v1; i2 = i1; v1 = sc; i1 = kk;
        } else if (sc > v2 || (sc == v2 && kk < i2)) {
          v2 = sc; i2 = kk;
        }
      }
    t2vg[(n0 + t) * 2] = v1; t2vg[(n0 + t) * 2 + 1] = v2;
    t2ig[(n0 + t) * 2] = i1; t2ig[(n0 + t) * 2 + 1] = i2;
  }

  // row max of nd (logits = 2*nd)
#pragma unroll
  for (int i = 0; i < 2; ++i)
#pragma unroll
    for (int r = 0; r < 4; ++r) {
      int rowloc = ng * 32 + i * 16 + g * 4 + r;
      float m = -3.0e38f;
#pragma unroll
      for (int j = 0; j < 16; ++j) m = fmaxf(m, acc[i][j][r]);
#pragma unroll
      for (int off = 1; off < 16; off <<= 1) m = fmaxf(m, __shfl_xor(m, off));
      if (c == 0) redfp[kg * 64 + rowloc] = m;
    }
  __syncthreads();  // B1
  if (t < 64)
    sxl[t] = 2.f * fmaxf(fmaxf(redfp[0 * 64 + t], redfp[1 * 64 + t]),
                         fmaxf(redfp[2 * 64 + t], redfp[3 * 64 + t]));
  __syncthreads();  // B2

  float rsum[2][4] = {};
#pragma unroll
  for (int i = 0; i < 2; ++i)
#pragma unroll
    for (int r = 0; r < 4; ++r) {
      float mm = sxl[ng * 32 + i * 16 + g * 4 + r];
#pragma unroll
      for (int j = 0; j < 16; ++j) {
        float e = __expf(fmaf(2.f, acc[i][j][r], -mm));
        acc[i][j][r] = e;
        rsum[i][r] += e;
      }
    }
#pragma unroll
  for (int i = 0; i < 2; ++i)
#pragma unroll
    for (int r = 0; r < 4; ++r) {
      float s = rsum[i][r];
#pragma unroll
      for (int off = 1; off < 16; off <<= 1) s += __shfl_xor(s, off);
      if (c == 0) redfp[kg * 64 + ng * 32 + i * 16 + g * 4 + r] = s;
    }
  __syncthreads();  // B3
  if (t < 64) sxl[t] = 1.0f / (redfp[0 * 64 + t] + redfp[1 * 64 + t] +
                               redfp[2 * 64 + t] + redfp[3 * 64 + t]);
  __syncthreads();  // B4

  float ent = 0.f;
#pragma unroll
  for (int i = 0; i < 2; ++i)
#pragma unroll
    for (int r = 0; r < 4; ++r) {
      float inv = sxl[ng * 32 + i * 16 + g * 4 + r];
#pragma unroll
      for (int j = 0; j < 16; ++j) {
        float sfv = acc[i][j][r] * inv;
        acc[i][j][r] = sfv;
        ent += sfv * __logf(fmaxf(sfv, 1e-8f));
      }
    }
#pragma unroll
  for (int off = 1; off < 64; off <<= 1) ent += __shfl_xor(ent, off);
  if (l == 0) bacc[wid] = ent;

  // transposed softT write via LDS slab, four k-quarters (tsl = 256*72 ushorts)
#pragma unroll
  for (int ph = 0; ph < 4; ++ph) {
    __syncthreads();
    if (kg == ph) {
#pragma unroll
      for (int i = 0; i < 2; ++i)
#pragma unroll
        for (int j = 0; j < 16; ++j)
#pragma unroll
          for (int r = 0; r < 4; ++r)
            tsl[(j * 16 + c) * 72 + ng * 32 + i * 16 + g * 4 + r] = f2bf(acc[i][j][r]);
    }
    __syncthreads();
#pragma unroll
    for (int p = 0; p < 4; ++p) {
      int idx = p * 512 + t;
      int kloc = idx >> 3, ch = idx & 7;
      *(uint4*)&softT[((size_t)(ph * 256 + kloc)) * NROWS + n0 + ch * 8] =
          *(uint4*)&tsl[kloc * 72 + ch * 8];
    }
  }
  __syncthreads();
  if (t == 0) {
    float s = 0.f;
#pragma unroll
    for (int q = 0; q < 8; ++q) s += bacc[q];
    bent[blockIdx.x] = s;
  }
}

// ---------------- exact argmax refinement of top-2 candidates ----------------
__global__ __launch_bounds__(256) void k_refine(const ushort* __restrict__ XS3,
                                                const float* __restrict__ w,
                                                const float* __restrict__ wsq,
                                                const float* __restrict__ xsq,
                                                const float* __restrict__ G,
                                                const int* __restrict__ t2ig,
                                                int* __restrict__ idxArr,
                                                float* __restrict__ hcnt) {
  int t = threadIdx.x;
  int l = t & 63, wv = t >> 6;
  int base = blockIdx.x * 64 + wv * 16;
  int d0 = l * 4;
  for (int rr = 0; rr < 16; ++rr) {
    int n = base + rr;
    const ushort* p = XS3 + (size_t)n * 768;
    union { uint2 q; ushort u[4]; } ha, ma, la;
    ha.q = *(const uint2*)&p[d0];
    ma.q = *(const uint2*)&p[256 + d0];
    la.q = *(const uint2*)&p[512 + d0];
    float xv[4];
#pragma unroll
    for (int q = 0; q < 4; ++q) xv[q] = bf2f(ha.u[q]) + bf2f(ma.u[q]) + bf2f(la.u[q]);
    float xs = xsq[n];
    int ia = t2ig[n * 2], ib = t2ig[n * 2 + 1];
    float sc[2];
    int ids[2] = {ia, ib};
#pragma unroll
    for (int cdd = 0; cdd < 2; ++cdd) {
      int id = ids[cdd];
      const float* wr = w + (size_t)id * DDIM;
      float4 wv4 = *(const float4*)&wr[d0];
      float d = xv[0] * wv4.x + xv[1] * wv4.y + xv[2] * wv4.z + xv[3] * wv4.w;
      d = wred_sum(d);
      sc[cdd] = fmaf(2.f, d, -xs) - wsq[id] + G[((size_t)n << 10) + id];
    }
    int win = (sc[1] > sc[0] || (sc[1] == sc[0] && ib < ia)) ? ib : ia;
    if (l == 0) {
      idxArr[n] = win;
      atomicAdd(&hcnt[win], 1.f);
    }
  }
}

// ---------------- quantized output: out[b,d,h,w] = w[idx[n], d] ----------------
__global__ void k_quant(const float* __restrict__ w, const int* __restrict__ idxArr,
                        float* __restrict__ outQ) {
  int n = blockIdx.x * 256 + threadIdx.x;
  int b = n >> 10, m = n & 1023;
  int id = idxArr[n];
  const float* wr = w + (size_t)id * DDIM;
  float* o = outQ + (size_t)b * DDIM * 1024 + m;
#pragma unroll 4
  for (int d = 0; d < DDIM; ++d) o[(size_t)d * 1024] = wr[d];
}

// ---------------- GEMM2 (MFMA bf16): dw[k,d] = sum_n soft[n,k] x[n,d] ----------------
// A = softT[k][n], B = xbf[b][d][m] (n = b*1024+m). Tile 256k x 128d, NT=64.
__global__ __launch_bounds__(512) void k_gemm2_mfma(const ushort* __restrict__ STbf,
                                                    const ushort* __restrict__ xbf,
                                                    float* __restrict__ P) {
  __shared__ __align__(16) ushort Abuf[256 * 72];
  __shared__ __align__(16) ushort Bbuf[128 * 72];
  int t = threadIdx.x;
  int bid = blockIdx.x;
  int kt = bid & 3, dt = (bid >> 2) & 1, ns = bid >> 3;
  int k0 = kt * 256, d0 = dt * 128;
  int l = t & 63, wv = t >> 6;
  int wk = wv >> 1, wd = wv & 1;
  f32x4 zero = {0.f, 0.f, 0.f, 0.f};
  f32x4 acc[4][4];
#pragma unroll
  for (int i = 0; i < 4; ++i)
#pragma unroll
    for (int j = 0; j < 4; ++j) acc[i][j] = zero;

  int colv = (t & 7) * 8;
  int rbase = t >> 3;
  for (int s = 0; s < 16; ++s) {
    size_t nb = (size_t)ns * 1024 + s * 64;
#pragma unroll
    for (int p = 0; p < 4; ++p) {
      int row = p * 64 + rbase;
      uint4 v = *(const uint4*)&STbf[(size_t)(k0 + row) * NROWS + nb + colv];
      *(uint4*)&Abuf[row * 72 + colv] = v;
    }
#pragma unroll
    for (int p = 0; p < 2; ++p) {
      int row = p * 64 + rbase;
      uint4 v = *(const uint4*)&xbf[((size_t)ns * DDIM + d0 + row) * 1024 + s * 64 + colv];
      *(uint4*)&Bbuf[row * 72 + colv] = v;
    }
    __syncthreads();
    bf16x8 af[4], bfr[4];
#pragma unroll
    for (int nb2 = 0; nb2 < 2; ++nb2) {
#pragma unroll
      for (int sub = 0; sub < 4; ++sub) {
        af[sub] = *(const bf16x8*)&Abuf[(wk * 64 + sub * 16 + (l & 15)) * 72 + nb2 * 32 + (l >> 4) * 8];
        bfr[sub] = *(const bf16x8*)&Bbuf[(wd * 64 + sub * 16 + (l & 15)) * 72 + nb2 * 32 + (l >> 4) * 8];
      }
#pragma unroll
      for (int i = 0; i < 4; ++i)
#pragma unroll
        for (int j = 0; j < 4; ++j)
          acc[i][j] = __builtin_amdgcn_mfma_f32_16x16x32_bf16(af[i], bfr[j], acc[i][j], 0, 0, 0);
    }
    __syncthreads();
  }
  float* Pb = P + (size_t)ns * (KCB * DDIM);
#pragma unroll
  for (int i = 0; i < 4; ++i)
#pragma unroll
    for (int j = 0; j < 4; ++j) {
#pragma unroll
      for (int r = 0; r < 4; ++r) {
        int k = k0 + wk * 64 + i * 16 + (l >> 4) * 4 + r;
        int d = d0 + wd * 64 + j * 16 + (l & 15);
        Pb[(size_t)k * DDIM + d] = acc[i][j][r];
      }
    }
}

// ---------------- colsum[k] = sum_n soft[n][k] (from softT rows) ----------------
__global__ void k_colsum(const ushort* __restrict__ STbf, float* __restrict__ colsum) {
  int k = blockIdx.x;
  int t = threadIdx.x;
  const ushort* row = STbf + (size_t)k * NROWS;
  float s = 0.f;
#pragma unroll
  for (int cc = 0; cc < 16; ++cc) {
    uint4 v = *(const uint4*)&row[cc * 2048 + t * 8];
    ushort* vp = (ushort*)&v;
#pragma unroll
    for (int j = 0; j < 8; ++j) s += bf2f(vp[j]);
  }
  s = wred_sum(s);
  __shared__ float ws4[4];
  if ((t & 63) == 0) ws4[t >> 6] = s;
  __syncthreads();
  if (t == 0) colsum[k] = ws4[0] + ws4[1] + ws4[2] + ws4[3];
}

// ---------------- finalize scalars, new_count ----------------
__global__ void k_final1(const float* __restrict__ ema_count, const float* __restrict__ colsum,
                         const float* __restrict__ hcnt, const float* __restrict__ bent,
                         float* __restrict__ ncnt, float* __restrict__ out) {
  __shared__ float red[1024];
  int t = threadIdx.x;
  const float onem = 1.0f - 0.99f;
  float nc = ema_count[t] * 0.99f + colsum[t] * onem;
  nc = (nc + 1e-5f) / (32768.0f + 1024.0f * 1e-5f) * 32768.0f;
  out[O_NCNT + t] = nc;
  ncnt[t] = nc;
  float s = 0.f;
  for (int i = t; i < 512; i += 1024) s += bent[i];
  red[t] = s;
  __syncthreads();
  for (int off = 512; off > 0; off >>= 1) { if (t < off) red[t] += red[t + off]; __syncthreads(); }
  if (t == 0) out[O_LOSS] = 0.25f * (red[0] / 32768.0f);
  __syncthreads();
  float avg = hcnt[t] * (1.0f / 32768.0f);
  red[t] = avg * logf(avg + 1e-10f);
  __syncthreads();
  for (int off = 512; off > 0; off >>= 1) { if (t < off) red[t] += red[t + off]; __syncthreads(); }
  if (t == 0) out[O_PERP] = expf(-red[0]);
}

// ---------------- reduce dw partials + new_ema_weight & new_embedding ----------------
__global__ void k_reduce_final2(const float* __restrict__ P, const float* __restrict__ ema_w,
                                const float* __restrict__ ncnt, float* __restrict__ outEW,
                                float* __restrict__ outEMB) {
  int i = blockIdx.x * 256 + threadIdx.x;
  float s = 0.f;
#pragma unroll
  for (int ns = 0; ns < 32; ++ns) s += P[(size_t)ns * (KCB * DDIM) + i];
  float ew = ema_w[i] * 0.99f + s * 0.01f;
  outEW[i] = ew;
  outEMB[i] = ew / ncnt[i >> 8];
}

// ---------------- one-hot encodings (overwrites E scratch) ----------------
__global__ void k_onehot(const int* __restrict__ idxArr, float* __restrict__ E) {
  int gid = blockIdx.x * 256 + threadIdx.x;
  int n = gid >> 8;
  int k4 = (gid & 255) * 4;
  int id = idxArr[n];
  float2* E2 = (float2*)E;
  size_t base = ((size_t)n * KCB + k4) >> 1;
  float2 vA = {(float)(k4 == id), (float)(k4 + 1 == id)};
  float2 vB = {(float)(k4 + 2 == id), (float)(k4 + 3 == id)};
  E2[base] = vA;
  E2[base + 1] = vB;
}

extern "C" void kernel_launch(void* const* d_in, const int* in_sizes, int n_in,
                              void* d_out, int out_size, void* d_ws, size_t ws_size,
                              hipStream_t stream) {
  const float* x = (const float*)d_in[0];
  const float* w = (const float*)d_in[1];
  const float* ema_count = (const float*)d_in[2];
  const float* ema_w = (const float*)d_in[3];
  const float* g = (const float*)d_in[4];
  float* out = (float*)d_out;
  float* ws = (float*)d_ws;

  float* wsq    = ws + W_WSQ;
  float* xsq    = ws + W_XSQ;
  int*   idxArr = (int*)(ws + W_IDX);
  float* colsum = ws + W_COL;
  float* hcnt   = ws + W_HCNT;
  float* bent   = ws + W_BENT;
  float* ncnt   = ws + W_NCNT;
  float* top2v  = ws + W_T2V;
  int*   top2i  = (int*)(ws + W_T2I);
  ushort* WB    = (ushort*)(ws + W_WB);

  float* outQ = out + O_Q;
  float* outE = out + O_ENC;

  ushort* XS3   = (ushort*)(outE + E_XS3);
  ushort* softT = (ushort*)(outE + E_SOFTT);
  ushort* xbf   = (ushort*)(outE + E_XBF);
  float*  P     = outQ;  // Q region scratch for GEMM2 partials (exact fit)

  k_init<<<4, 256, 0, stream>>>(hcnt);
  k_wsplit<<<256, 256, 0, stream>>>(w, wsq, WB);
  k_xsplit<<<1024, 256, 0, stream>>>(x, XS3, xbf, xsq);
  k_score<<<512, 512, 0, stream>>>(XS3, WB, g, wsq, xsq, softT, bent, top2v, top2i);
  k_refine<<<512, 256, 0, stream>>>(XS3, w, wsq, xsq, g, top2i, idxArr, hcnt);
  k_colsum<<<1024, 256, 0, stream>>>(softT, colsum);
  k_gemm2_mfma<<<256, 512, 0, stream>>>(softT, xbf, P);
  k_final1<<<1, 1024, 0, stream>>>(ema_count, colsum, hcnt, bent, ncnt, out);
  k_reduce_final2<<<1024, 256, 0, stream>>>(P, ema_w, ncnt, out + O_EMAW, out + O_EMB);
  k_quant<<<128, 256, 0, stream>>>(w, idxArr, outQ);
  k_onehot<<<32768, 256, 0, stream>>>(idxArr, outE);
}

// Round 8
// 509.461 us; speedup vs baseline: 2.7539x; 2.7539x over previous
//
#include <hip/hip_runtime.h>
#include <math.h>

// Problem constants
#define NROWS 32768   // B*H*W
#define KCB   1024
#define DDIM  256
#define NHALF 16384

// Output offsets (floats)
#define O_LOSS 0
#define O_Q    1
#define O_PERP 8388609
#define O_ENC  8388610
#define O_NCNT 41943042
#define O_EMAW 41944066
#define O_EMB  42206210

// E-region scratch (floats rel. outE; region = 33,554,432 floats):
//   XS3   @ 2          : bf16 [32768][768] (hi|mid|lo) = 12,582,912 floats (16B-aligned)
//   Sslot @ 12582914   : fp32 [16384][1024] = 16,777,216 floats -> ends 29,360,130 (< region end)
//   softT1 aliases XS3 base (written after refine); P partials alias Sslot head.
#define E_XS3   2
#define E_S     12582914

// Workspace offsets (floats)
#define W_WSQ  0        // 1024
#define W_XSQ  1024     // 32768
#define W_IDX  33792    // 32768 (int)
#define W_COL  66560    // 1024
#define W_HCNT 67584    // 1024
#define W_BENT 68608    // 8192
#define W_NCNT 76800    // 1024
#define W_T2I  77824    // 65536 (int)
#define W_WB   143360   // 1024*768 ushorts = 393216 floats
// total 536,576 floats = 2.15 MB

typedef __attribute__((ext_vector_type(8))) short bf16x8;
typedef __attribute__((ext_vector_type(4))) float f32x4;

#define GLOAD_LDS16(g, l) __builtin_amdgcn_global_load_lds( \
    (const __attribute__((address_space(1))) unsigned int*)(g), \
    (__attribute__((address_space(3))) unsigned int*)(l), 16, 0, 0)

__device__ __forceinline__ float wred_sum(float v) {
#pragma unroll
  for (int off = 32; off > 0; off >>= 1) v += __shfl_xor(v, off);
  return v;
}
__device__ __forceinline__ ushort f2bf(float f) {
  union { float f; unsigned u; } c; c.f = f;
  unsigned u = c.u;
  return (ushort)((u + 0x7fffu + ((u >> 16) & 1u)) >> 16);  // RNE
}
__device__ __forceinline__ float bf2f(ushort h) {
  union { unsigned u; float f; } c; c.u = ((unsigned)h) << 16;
  return c.f;
}

// ---------------- init ----------------
__global__ void k_init(float* __restrict__ hcnt) {
  int i = blockIdx.x * 256 + threadIdx.x;
  if (i < 1024) hcnt[i] = 0.f;
}

// ---------------- w -> wsq + WB [k][768] = [w_hi | w_hi | w_mid] ----------------
__global__ void k_wsplit(const float* __restrict__ w, float* __restrict__ wsq,
                         ushort* __restrict__ WB) {
  int t = threadIdx.x;
  int lane = t & 63, wv = t >> 6;
  int k = blockIdx.x * 4 + wv;
  int d0 = lane * 4;
  float4 v = *(const float4*)&w[(size_t)k * DDIM + d0];
  float s = v.x * v.x + v.y * v.y + v.z * v.z + v.w * v.w;
  s = wred_sum(s);
  if (lane == 0) wsq[k] = s;
  float vv[4] = {v.x, v.y, v.z, v.w};
  union { ushort u[4]; uint2 q; } hh, mm;
#pragma unroll
  for (int q = 0; q < 4; ++q) {
    ushort h = f2bf(vv[q]);
    float r = vv[q] - bf2f(h);
    hh.u[q] = h;
    mm.u[q] = f2bf(r);
  }
  ushort* row = WB + (size_t)k * 768;
  *(uint2*)&row[d0] = hh.q;
  *(uint2*)&row[256 + d0] = hh.q;
  *(uint2*)&row[512 + d0] = mm.q;
}

// ---------------- x -> XS3 (3-way bf16 split) + xsq ----------------
__global__ __launch_bounds__(256) void k_xsplit(const float* __restrict__ x,
                                                ushort* __restrict__ XS3,
                                                float* __restrict__ xsq) {
  __shared__ __align__(16) ushort sl[32 * 776];
  __shared__ float sq[32 * 9];
  int t = threadIdx.x;
  int b = blockIdx.x >> 5, mt = blockIdx.x & 31;
  int m0 = mt * 32, mloc = t & 31, dgrp = t >> 5;
  const float* xb = x + (size_t)b * DDIM * 1024 + m0 + mloc;
  float s = 0.f;
#pragma unroll
  for (int jj = 0; jj < 8; ++jj) {
    int d0 = dgrp * 32 + jj * 4;
    float vv[4];
#pragma unroll
    for (int q = 0; q < 4; ++q) vv[q] = xb[(size_t)(d0 + q) * 1024];
    union { ushort u[4]; uint2 q; } hh, mi, lo;
#pragma unroll
    for (int q = 0; q < 4; ++q) {
      float v = vv[q];
      ushort h = f2bf(v);
      float r1 = v - bf2f(h);
      ushort m_ = f2bf(r1);
      float r2 = r1 - bf2f(m_);
      hh.u[q] = h; mi.u[q] = m_; lo.u[q] = f2bf(r2);
      s = fmaf(v, v, s);
    }
    int base = mloc * 776;
    *(uint2*)&sl[base + d0] = hh.q;
    *(uint2*)&sl[base + 256 + d0] = mi.q;
    *(uint2*)&sl[base + 512 + d0] = lo.q;
  }
  sq[mloc * 9 + dgrp] = s;
  __syncthreads();
  if (t < 32) {
    float ss = 0.f;
#pragma unroll
    for (int gq = 0; gq < 8; ++gq) ss += sq[t * 9 + gq];
    xsq[b * 1024 + m0 + t] = ss;
  }
  ushort* dst = XS3 + (size_t)(b * 1024 + m0) * 768;
#pragma unroll
  for (int p = 0; p < 12; ++p) {
    int idx = p * 256 + t;
    int row = idx / 96;
    int co = idx - row * 96;
    *(uint4*)&dst[(size_t)row * 768 + co * 8] = *(uint4*)&sl[row * 776 + co * 8];
  }
}

// ---------------- GEMM1 half: S[nloc][1024] = nd ; per-row top2 partials ----------------
// (structure validated in round 7: argmax/loss/perp/count all passed)
__global__ __launch_bounds__(256) void k_gemm1t(const ushort* __restrict__ XS3h,
                                                const ushort* __restrict__ WB,
                                                const float* __restrict__ Gh,
                                                const float* __restrict__ wsq,
                                                const float* __restrict__ xsqh,
                                                float* __restrict__ S,
                                                float* __restrict__ t2pv,
                                                int* __restrict__ t2pi) {
  __shared__ __align__(16) ushort Asl[8192];
  __shared__ __align__(16) ushort Bsl[8192];
  __shared__ float xsl[128];
  __shared__ float wsl[128];
  __shared__ float t2sv[4][64][2];
  __shared__ int   t2si[4][64][2];
  int t = threadIdx.x;
  int kt = blockIdx.x;
  int n0 = blockIdx.y * 128;
  int k0 = kt * 128;
  int l = t & 63, wid = t >> 6;
  int wr = wid >> 1, wc = wid & 1;
  int hi = l >> 4, c = l & 15;

  if (t < 128) { xsl[t] = xsqh[n0 + t]; wsl[t] = wsq[k0 + t]; }

  f32x4 zero = {0.f, 0.f, 0.f, 0.f};
  f32x4 acc[4][4];
#pragma unroll
  for (int i = 0; i < 4; ++i)
#pragma unroll
    for (int j = 0; j < 4; ++j) acc[i][j] = zero;

  const char* XSb = (const char*)XS3h;
  const char* WBb = (const char*)WB;
  char* AslB = (char*)Asl;
  char* BslB = (char*)Bsl;
  int lr = l >> 3;                      // row within 8-row DMA segment
  int lsw = ((l & 7) ^ lr) << 4;        // pre-swizzled source chunk byte

  for (int s = 0; s < 12; ++s) {
    size_t bofs = (size_t)s << 7;
    size_t aofs = (size_t)((s < 8) ? s : s - 8) << 7;
#pragma unroll
    for (int q = 0; q < 4; ++q) {
      int seg = wid * 32 + q * 8;
      GLOAD_LDS16(XSb + (size_t)(n0 + seg + lr) * 1536 + aofs + lsw, AslB + seg * 128);
      GLOAD_LDS16(WBb + (size_t)(k0 + seg + lr) * 1536 + bofs + lsw, BslB + seg * 128);
    }
    asm volatile("s_waitcnt vmcnt(0)" ::: "memory");
    __builtin_amdgcn_s_barrier();
    __builtin_amdgcn_sched_barrier(0);
#pragma unroll
    for (int kk = 0; kk < 2; ++kk) {
      bf16x8 af[4], bg[4];
#pragma unroll
      for (int i = 0; i < 4; ++i) {
        int row = wr * 64 + i * 16 + c;
        int ch = (kk * 4 + hi) ^ (row & 7);
        af[i] = *(const bf16x8*)&Asl[row * 64 + ch * 8];
      }
#pragma unroll
      for (int j = 0; j < 4; ++j) {
        int row = wc * 64 + j * 16 + c;
        int ch = (kk * 4 + hi) ^ (row & 7);
        bg[j] = *(const bf16x8*)&Bsl[row * 64 + ch * 8];
      }
#pragma unroll
      for (int i = 0; i < 4; ++i)
#pragma unroll
        for (int j = 0; j < 4; ++j)
          acc[i][j] = __builtin_amdgcn_mfma_f32_16x16x32_bf16(af[i], bg[j], acc[i][j], 0, 0, 0);
    }
    __syncthreads();
  }

  // epilogue: nd, S store, per-row top2
#pragma unroll
  for (int i = 0; i < 4; ++i) {
#pragma unroll
    for (int r = 0; r < 4; ++r) {
      int nl = wr * 64 + i * 16 + hi * 4 + r;
      float xs = xsl[nl];
      float v1 = -3.0e38f, v2 = -3.0e38f;
      int i1 = 0x7fffffff, i2 = 0x7fffffff;
#pragma unroll
      for (int j = 0; j < 4; ++j) {
        int kl = wc * 64 + j * 16 + c;
        float nd = fmaf(2.f, acc[i][j][r], -(xs + wsl[kl]));
        S[(size_t)(n0 + nl) * 1024 + k0 + kl] = nd;
        float sc = nd + Gh[(((size_t)(n0 + nl)) << 10) + k0 + kl];
        int kk2 = k0 + kl;
        if (sc > v1 || (sc == v1 && kk2 < i1)) { v2 = v1; i2 = i1; v1 = sc; i1 = kk2; }
        else if (sc > v2 || (sc == v2 && kk2 < i2)) { v2 = sc; i2 = kk2; }
      }
#pragma unroll
      for (int off = 1; off < 16; off <<= 1) {
        float ov1 = __shfl_xor(v1, off), ov2 = __shfl_xor(v2, off);
        int oi1 = __shfl_xor(i1, off), oi2 = __shfl_xor(i2, off);
        bool fB = (ov1 > v1) || (ov1 == v1 && oi1 < i1);
        float nv1 = fB ? ov1 : v1; int ni1 = fB ? oi1 : i1;
        float ca = fB ? v1 : ov1;  int cia = fB ? i1 : oi1;
        float cb = fB ? ov2 : v2;  int cib = fB ? oi2 : i2;
        bool sB = (cb > ca) || (cb == ca && cib < cia);
        v1 = nv1; i1 = ni1;
        v2 = sB ? cb : ca; i2 = sB ? cib : cia;
      }
      if (c == 0) {
        int rl = i * 16 + hi * 4 + r;
        t2sv[wid][rl][0] = v1; t2sv[wid][rl][1] = v2;
        t2si[wid][rl][0] = i1; t2si[wid][rl][1] = i2;
      }
    }
  }
  __syncthreads();
  if (t < 128) {
    int wr2 = t >> 6, rl = t & 63;
    float v1 = -3.0e38f, v2 = -3.0e38f;
    int i1 = 0x7fffffff, i2 = 0x7fffffff;
#pragma unroll
    for (int wq2 = 0; wq2 < 2; ++wq2) {
      int wvv = wr2 * 2 + wq2;
#pragma unroll
      for (int u = 0; u < 2; ++u) {
        float sc = t2sv[wvv][rl][u]; int kk2 = t2si[wvv][rl][u];
        if (sc > v1 || (sc == v1 && kk2 < i1)) { v2 = v1; i2 = i1; v1 = sc; i1 = kk2; }
        else if (sc > v2 || (sc == v2 && kk2 < i2)) { v2 = sc; i2 = kk2; }
      }
    }
    size_t o = ((size_t)kt * NHALF + n0 + t) * 2;
    t2pv[o] = v1; t2pv[o + 1] = v2;
    t2pi[o] = i1; t2pi[o + 1] = i2;
  }
}

// ---------------- merge 8 k-slice top2 partials -> t2ig (per half) ----------------
__global__ void k_t2merge(const float* __restrict__ t2pv, const int* __restrict__ t2pi,
                          int* __restrict__ t2igh) {
  int n = blockIdx.x * 256 + threadIdx.x;  // 0..16383
  float v1 = -3.0e38f, v2 = -3.0e38f;
  int i1 = 0x7fffffff, i2 = 0x7fffffff;
  for (int sl = 0; sl < 8; ++sl) {
    size_t o = ((size_t)sl * NHALF + n) * 2;
#pragma unroll
    for (int u = 0; u < 2; ++u) {
      float sc = t2pv[o + u]; int kk = t2pi[o + u];
      if (sc > v1 || (sc == v1 && kk < i1)) { v2 = v1; i2 = i1; v1 = sc; i1 = kk; }
      else if (sc > v2 || (sc == v2 && kk < i2)) { v2 = sc; i2 = kk; }
    }
  }
  t2igh[n * 2] = i1; t2igh[n * 2 + 1] = i2;
}

// ---------------- streaming softmax in place (per half) ----------------
__global__ __launch_bounds__(256) void k_rowops2(float* __restrict__ S,
                                                 float* __restrict__ benth) {
  __shared__ float went[4];
  int t = threadIdx.x;
  int l = t & 63, wv = t >> 6;
  int n = blockIdx.x * 4 + wv;
  float* row = S + ((size_t)n << 10);
  float v[16];
  float mx = -3.0e38f;
#pragma unroll
  for (int j = 0; j < 4; ++j) {
    float4 a = *(const float4*)&row[j * 256 + l * 4];
    v[j * 4 + 0] = a.x; v[j * 4 + 1] = a.y; v[j * 4 + 2] = a.z; v[j * 4 + 3] = a.w;
    mx = fmaxf(mx, fmaxf(fmaxf(a.x, a.y), fmaxf(a.z, a.w)));
  }
#pragma unroll
  for (int off = 1; off < 64; off <<= 1) mx = fmaxf(mx, __shfl_xor(mx, off));
  float M = 2.f * mx;
  float e[16]; float ps = 0.f;
#pragma unroll
  for (int u = 0; u < 16; ++u) { e[u] = __expf(fmaf(2.f, v[u], -M)); ps += e[u]; }
  ps = wred_sum(ps);
  float inv = 1.f / ps;
  float ent = 0.f;
#pragma unroll
  for (int j = 0; j < 4; ++j) {
    float4 o;
    float s0 = e[j * 4 + 0] * inv, s1 = e[j * 4 + 1] * inv;
    float s2 = e[j * 4 + 2] * inv, s3 = e[j * 4 + 3] * inv;
    ent += s0 * __logf(fmaxf(s0, 1e-8f)) + s1 * __logf(fmaxf(s1, 1e-8f));
    ent += s2 * __logf(fmaxf(s2, 1e-8f)) + s3 * __logf(fmaxf(s3, 1e-8f));
    o.x = s0; o.y = s1; o.z = s2; o.w = s3;
    *(float4*)&row[j * 256 + l * 4] = o;
  }
  ent = wred_sum(ent);
  if (l == 0) went[wv] = ent;
  __syncthreads();
  if (t == 0) benth[blockIdx.x] = went[0] + went[1] + went[2] + went[3];
}

// ---------------- transpose soft fp32 [16384][1024] -> softT panel bf16 [1024][16384] ----------------
__global__ void k_transpose2(const float* __restrict__ soft, ushort* __restrict__ sTp) {
  __shared__ ushort lds[64 * 65];
  int t = threadIdx.x;
  int ktile = blockIdx.x & 15, nt = blockIdx.x >> 4;
  int n0 = nt * 64, k0 = ktile * 64;
#pragma unroll
  for (int p = 0; p < 2; ++p) {
    int row = p * 32 + (t >> 3);
    int c8 = (t & 7) * 8;
    float4 a = *(const float4*)&soft[(size_t)(n0 + row) * 1024 + k0 + c8];
    float4 b = *(const float4*)&soft[(size_t)(n0 + row) * 1024 + k0 + c8 + 4];
    ushort* d = &lds[row * 65 + c8];
    d[0] = f2bf(a.x); d[1] = f2bf(a.y); d[2] = f2bf(a.z); d[3] = f2bf(a.w);
    d[4] = f2bf(b.x); d[5] = f2bf(b.y); d[6] = f2bf(b.z); d[7] = f2bf(b.w);
  }
  __syncthreads();
#pragma unroll
  for (int p = 0; p < 2; ++p) {
    int krow = p * 32 + (t >> 3);
    int nc8 = (t & 7) * 8;
    uint* dst = (uint*)&sTp[(size_t)(k0 + krow) * NHALF + n0 + nc8];
#pragma unroll
    for (int j = 0; j < 4; ++j) {
      uint lo = lds[(nc8 + 2 * j) * 65 + krow];
      uint hh = lds[(nc8 + 2 * j + 1) * 65 + krow];
      dst[j] = lo | (hh << 16);
    }
  }
}

// ---------------- exact argmax refinement ----------------
__global__ __launch_bounds__(256) void k_refine(const ushort* __restrict__ XS3,
                                                const float* __restrict__ w,
                                                const float* __restrict__ wsq,
                                                const float* __restrict__ xsq,
                                                const float* __restrict__ G,
                                                const int* __restrict__ t2ig,
                                                int* __restrict__ idxArr,
                                                float* __restrict__ hcnt) {
  int t = threadIdx.x;
  int l = t & 63, wv = t >> 6;
  int base = blockIdx.x * 64 + wv * 16;
  int d0 = l * 4;
  for (int rr = 0; rr < 16; ++rr) {
    int n = base + rr;
    const ushort* p = XS3 + (size_t)n * 768;
    union { uint2 q; ushort u[4]; } ha, ma, la;
    ha.q = *(const uint2*)&p[d0];
    ma.q = *(const uint2*)&p[256 + d0];
    la.q = *(const uint2*)&p[512 + d0];
    float xv[4];
#pragma unroll
    for (int q = 0; q < 4; ++q) xv[q] = bf2f(ha.u[q]) + bf2f(ma.u[q]) + bf2f(la.u[q]);
    float xs = xsq[n];
    int ia = t2ig[n * 2], ib = t2ig[n * 2 + 1];
    float sc[2];
    int ids[2] = {ia, ib};
#pragma unroll
    for (int cdd = 0; cdd < 2; ++cdd) {
      int id = ids[cdd];
      const float* wr = w + (size_t)id * DDIM;
      float4 wv4 = *(const float4*)&wr[d0];
      float d = xv[0] * wv4.x + xv[1] * wv4.y + xv[2] * wv4.z + xv[3] * wv4.w;
      d = wred_sum(d);
      sc[cdd] = fmaf(2.f, d, -xs) - wsq[id] + G[((size_t)n << 10) + id];
    }
    int win = (sc[1] > sc[0] || (sc[1] == sc[0] && ib < ia)) ? ib : ia;
    if (l == 0) {
      idxArr[n] = win;
      atomicAdd(&hcnt[win], 1.f);
    }
  }
}

// ---------------- quantized output ----------------
__global__ void k_quant(const float* __restrict__ w, const int* __restrict__ idxArr,
                        float* __restrict__ outQ) {
  int n = blockIdx.x * 256 + threadIdx.x;
  int b = n >> 10, m = n & 1023;
  int id = idxArr[n];
  const float* wr = w + (size_t)id * DDIM;
  float* o = outQ + (size_t)b * DDIM * 1024 + m;
#pragma unroll 4
  for (int d = 0; d < DDIM; ++d) o[(size_t)d * 1024] = wr[d];
}

// ---------------- GEMM2 (MFMA bf16): dw = soft^T x ; B staged from fp32 x ----------------
__global__ __launch_bounds__(512) void k_gemm2_mfma(const ushort* __restrict__ sT0,
                                                    const ushort* __restrict__ sT1,
                                                    const float* __restrict__ x,
                                                    float* __restrict__ P) {
  __shared__ __align__(16) ushort Abuf[256 * 72];
  __shared__ __align__(16) ushort Bbuf[128 * 72];
  int t = threadIdx.x;
  int bid = blockIdx.x;
  int kt = bid & 3, dt = (bid >> 2) & 1, ns = bid >> 3;
  int k0 = kt * 256, d0 = dt * 128;
  int l = t & 63, wv = t >> 6;
  int wk = wv >> 1, wd = wv & 1;
  const ushort* Abase = (ns < 16) ? sT0 : sT1;
  size_t nloc0 = (size_t)(ns & 15) * 1024;
  f32x4 zero = {0.f, 0.f, 0.f, 0.f};
  f32x4 acc[4][4];
#pragma unroll
  for (int i = 0; i < 4; ++i)
#pragma unroll
    for (int j = 0; j < 4; ++j) acc[i][j] = zero;

  int colv = (t & 7) * 8;
  int rbase = t >> 3;
  for (int s = 0; s < 16; ++s) {
#pragma unroll
    for (int p = 0; p < 4; ++p) {
      int row = p * 64 + rbase;
      const uint* ap = (const uint*)(Abase + (size_t)(k0 + row) * NHALF + nloc0 + s * 64 + colv);
      uint4 v; v.x = ap[0]; v.y = ap[1]; v.z = ap[2]; v.w = ap[3];
      *(uint4*)&Abuf[row * 72 + colv] = v;
    }
#pragma unroll
    for (int p = 0; p < 2; ++p) {
      int row = p * 64 + rbase;
      const float* xp = &x[((size_t)ns * DDIM + d0 + row) * 1024 + s * 64 + colv];
      float4 a = *(const float4*)xp;
      float4 b = *(const float4*)(xp + 4);
      union { ushort u[8]; uint4 q; } pk;
      pk.u[0] = f2bf(a.x); pk.u[1] = f2bf(a.y); pk.u[2] = f2bf(a.z); pk.u[3] = f2bf(a.w);
      pk.u[4] = f2bf(b.x); pk.u[5] = f2bf(b.y); pk.u[6] = f2bf(b.z); pk.u[7] = f2bf(b.w);
      *(uint4*)&Bbuf[row * 72 + colv] = pk.q;
    }
    __syncthreads();
    bf16x8 af[4], bfr[4];
#pragma unroll
    for (int nb2 = 0; nb2 < 2; ++nb2) {
#pragma unroll
      for (int sub = 0; sub < 4; ++sub) {
        af[sub] = *(const bf16x8*)&Abuf[(wk * 64 + sub * 16 + (l & 15)) * 72 + nb2 * 32 + (l >> 4) * 8];
        bfr[sub] = *(const bf16x8*)&Bbuf[(wd * 64 + sub * 16 + (l & 15)) * 72 + nb2 * 32 + (l >> 4) * 8];
      }
#pragma unroll
      for (int i = 0; i < 4; ++i)
#pragma unroll
        for (int j = 0; j < 4; ++j)
          acc[i][j] = __builtin_amdgcn_mfma_f32_16x16x32_bf16(af[i], bfr[j], acc[i][j], 0, 0, 0);
    }
    __syncthreads();
  }
  float* Pb = P + (size_t)ns * (KCB * DDIM);
#pragma unroll
  for (int i = 0; i < 4; ++i)
#pragma unroll
    for (int j = 0; j < 4; ++j) {
#pragma unroll
      for (int r = 0; r < 4; ++r) {
        int k = k0 + wk * 64 + i * 16 + (l >> 4) * 4 + r;
        int d = d0 + wd * 64 + j * 16 + (l & 15);
        Pb[(size_t)k * DDIM + d] = acc[i][j][r];
      }
    }
}

// ---------------- colsum over two softT panels ----------------
__global__ void k_colsum2(const ushort* __restrict__ sT0, const ushort* __restrict__ sT1,
                          float* __restrict__ colsum) {
  int k = blockIdx.x;
  int t = threadIdx.x;
  const uint* r0 = (const uint*)(sT0 + (size_t)k * NHALF);
  const uint* r1 = (const uint*)(sT1 + (size_t)k * NHALF);
  float s = 0.f;
#pragma unroll
  for (int cc = 0; cc < 8; ++cc) {
#pragma unroll
    for (int q = 0; q < 4; ++q) {
      uint a = r0[cc * 1024 + t * 4 + q];
      uint b = r1[cc * 1024 + t * 4 + q];
      s += bf2f((ushort)(a & 0xffffu)) + bf2f((ushort)(a >> 16));
      s += bf2f((ushort)(b & 0xffffu)) + bf2f((ushort)(b >> 16));
    }
  }
  s = wred_sum(s);
  __shared__ float ws4[4];
  if ((t & 63) == 0) ws4[t >> 6] = s;
  __syncthreads();
  if (t == 0) colsum[k] = ws4[0] + ws4[1] + ws4[2] + ws4[3];
}

// ---------------- finalize scalars, new_count ----------------
__global__ void k_final1(const float* __restrict__ ema_count, const float* __restrict__ colsum,
                         const float* __restrict__ hcnt, const float* __restrict__ bent,
                         float* __restrict__ ncnt, float* __restrict__ out) {
  __shared__ float red[1024];
  int t = threadIdx.x;
  const float onem = 1.0f - 0.99f;
  float nc = ema_count[t] * 0.99f + colsum[t] * onem;
  nc = (nc + 1e-5f) / (32768.0f + 1024.0f * 1e-5f) * 32768.0f;
  out[O_NCNT + t] = nc;
  ncnt[t] = nc;
  float s = 0.f;
  for (int i = t; i < 8192; i += 1024) s += bent[i];
  red[t] = s;
  __syncthreads();
  for (int off = 512; off > 0; off >>= 1) { if (t < off) red[t] += red[t + off]; __syncthreads(); }
  if (t == 0) out[O_LOSS] = 0.25f * (red[0] / 32768.0f);
  __syncthreads();
  float avg = hcnt[t] * (1.0f / 32768.0f);
  red[t] = avg * logf(avg + 1e-10f);
  __syncthreads();
  for (int off = 512; off > 0; off >>= 1) { if (t < off) red[t] += red[t + off]; __syncthreads(); }
  if (t == 0) out[O_PERP] = expf(-red[0]);
}

// ---------------- reduce dw partials + new_ema_weight & new_embedding ----------------
__global__ void k_reduce_final2(const float* __restrict__ P, const float* __restrict__ ema_w,
                                const float* __restrict__ ncnt, float* __restrict__ outEW,
                                float* __restrict__ outEMB) {
  int i = blockIdx.x * 256 + threadIdx.x;
  float s = 0.f;
#pragma unroll
  for (int ns = 0; ns < 32; ++ns) s += P[(size_t)ns * (KCB * DDIM) + i];
  float ew = ema_w[i] * 0.99f + s * 0.01f;
  outEW[i] = ew;
  outEMB[i] = ew / ncnt[i >> 8];
}

// ---------------- one-hot encodings (overwrites E scratch, last) ----------------
__global__ void k_onehot(const int* __restrict__ idxArr, float* __restrict__ E) {
  int gid = blockIdx.x * 256 + threadIdx.x;
  int n = gid >> 8;
  int k4 = (gid & 255) * 4;
  int id = idxArr[n];
  float2* E2 = (float2*)E;
  size_t base = ((size_t)n * KCB + k4) >> 1;
  float2 vA = {(float)(k4 == id), (float)(k4 + 1 == id)};
  float2 vB = {(float)(k4 + 2 == id), (float)(k4 + 3 == id)};
  E2[base] = vA;
  E2[base + 1] = vB;
}

extern "C" void kernel_launch(void* const* d_in, const int* in_sizes, int n_in,
                              void* d_out, int out_size, void* d_ws, size_t ws_size,
                              hipStream_t stream) {
  const float* x = (const float*)d_in[0];
  const float* w = (const float*)d_in[1];
  const float* ema_count = (const float*)d_in[2];
  const float* ema_w = (const float*)d_in[3];
  const float* g = (const float*)d_in[4];
  float* out = (float*)d_out;
  float* ws = (float*)d_ws;

  float* wsq    = ws + W_WSQ;
  float* xsq    = ws + W_XSQ;
  int*   idxArr = (int*)(ws + W_IDX);
  float* colsum = ws + W_COL;
  float* hcnt   = ws + W_HCNT;
  float* bent   = ws + W_BENT;
  float* ncnt   = ws + W_NCNT;
  int*   top2i  = (int*)(ws + W_T2I);
  ushort* WB    = (ushort*)(ws + W_WB);

  float* outQ = out + O_Q;
  float* outE = out + O_ENC;

  ushort* XS3    = (ushort*)(outE + E_XS3);     // 16B-aligned
  float*  Sslot  = outE + E_S;                  // 16B-aligned; ends before region end
  ushort* softT1 = (ushort*)(outE + E_XS3);     // overwrites XS3 after refine
  ushort* softT0 = (ushort*)outQ;               // Q region (4B-aligned: uint ops only)
  float*  t2pv0  = outQ;                        // Q head, dead before softT0 written
  int*    t2pi0  = (int*)(outQ + 262144);
  float*  t2pv1  = out + O_NCNT;                // NCNT/EMAW/EMB window, overwritten by finals
  int*    t2pi1  = (int*)(out + O_NCNT + 262144);

  k_init<<<4, 256, 0, stream>>>(hcnt);
  k_wsplit<<<256, 256, 0, stream>>>(w, wsq, WB);
  k_xsplit<<<1024, 256, 0, stream>>>(x, XS3, xsq);
  // ---- half 0 (rows 0..16383) ----
  k_gemm1t<<<dim3(8, 128), 256, 0, stream>>>(XS3, WB, g, wsq, xsq, Sslot, t2pv0, t2pi0);
  k_t2merge<<<64, 256, 0, stream>>>(t2pv0, t2pi0, top2i);
  k_rowops2<<<4096, 256, 0, stream>>>(Sslot, bent);
  k_transpose2<<<4096, 256, 0, stream>>>(Sslot, softT0);   // -> Q (t2p0 dead)
  // ---- half 1 (rows 16384..32767) ----
  k_gemm1t<<<dim3(8, 128), 256, 0, stream>>>(XS3 + (size_t)NHALF * 768, WB,
                                             g + (size_t)NHALF * 1024, wsq,
                                             xsq + NHALF, Sslot, t2pv1, t2pi1);
  k_t2merge<<<64, 256, 0, stream>>>(t2pv1, t2pi1, top2i + NHALF * 2);
  k_rowops2<<<4096, 256, 0, stream>>>(Sslot, bent + 4096);
  k_refine<<<512, 256, 0, stream>>>(XS3, w, wsq, xsq, g, top2i, idxArr, hcnt);
  k_transpose2<<<4096, 256, 0, stream>>>(Sslot, softT1);   // overwrites XS3 front (refine done)
  k_colsum2<<<1024, 256, 0, stream>>>(softT0, softT1, colsum);
  k_gemm2_mfma<<<256, 512, 0, stream>>>(softT0, softT1, x, Sslot);  // P -> Sslot head
  k_final1<<<1, 1024, 0, stream>>>(ema_count, colsum, hcnt, bent, ncnt, out);  // overwrites t2p1 head
  k_reduce_final2<<<1024, 256, 0, stream>>>(Sslot, ema_w, ncnt, out + O_EMAW, out + O_EMB);
  k_quant<<<128, 256, 0, stream>>>(w, idxArr, outQ);       // overwrites softT0
  k_onehot<<<32768, 256, 0, stream>>>(idxArr, outE);       // overwrites all E scratch
}

// Round 9
// 402.631 us; speedup vs baseline: 3.4845x; 1.2653x over previous
//
#include <hip/hip_runtime.h>
#include <math.h>

// Problem constants
#define NROWS 32768   // B*H*W
#define KCB   1024
#define DDIM  256
#define NHALF 16384

// Output offsets (floats)
#define O_LOSS 0
#define O_Q    1
#define O_PERP 8388609
#define O_ENC  8388610
#define O_NCNT 41943042
#define O_EMAW 41944066
#define O_EMB  42206210

// E-region scratch (floats rel. outE; region = 33,554,432 floats):
//   XS3   @ 2          : bf16 [32768][768] (hi|mid|lo) = 12,582,912 floats (16B-aligned)
//   Sslot @ 12582914   : fp32 [16384][1024] = 16,777,216 floats -> ends 29,360,130
//   softT1 aliases XS3 base (written after refine); P partials alias Sslot head.
#define E_XS3   2
#define E_S     12582914

// Workspace offsets (floats)
#define W_WSQ  0        // 1024
#define W_XSQ  1024     // 32768
#define W_IDX  33792    // 32768 (int)
#define W_COL  66560    // 1024
#define W_HCNT 67584    // 1024
#define W_BENT 68608    // 8192
#define W_NCNT 76800    // 1024
#define W_T2I  77824    // 65536 (int)
#define W_WB   143360   // 1024*768 ushorts = 393216 floats

typedef __attribute__((ext_vector_type(8))) short bf16x8;
typedef __attribute__((ext_vector_type(4))) float f32x4;

#define GLOAD_LDS16(g, l) __builtin_amdgcn_global_load_lds( \
    (const __attribute__((address_space(1))) unsigned int*)(g), \
    (__attribute__((address_space(3))) unsigned int*)(l), 16, 0, 0)

__device__ __forceinline__ float wred_sum(float v) {
#pragma unroll
  for (int off = 32; off > 0; off >>= 1) v += __shfl_xor(v, off);
  return v;
}
__device__ __forceinline__ ushort f2bf(float f) {
  union { float f; unsigned u; } c; c.f = f;
  unsigned u = c.u;
  return (ushort)((u + 0x7fffu + ((u >> 16) & 1u)) >> 16);  // RNE
}
__device__ __forceinline__ float bf2f(ushort h) {
  union { unsigned u; float f; } c; c.u = ((unsigned)h) << 16;
  return c.f;
}

// ---------------- init ----------------
__global__ void k_init(float* __restrict__ hcnt) {
  int i = blockIdx.x * 256 + threadIdx.x;
  if (i < 1024) hcnt[i] = 0.f;
}

// ---------------- w -> wsq + WB [k][768] = [w_hi | w_hi | w_mid] ----------------
__global__ void k_wsplit(const float* __restrict__ w, float* __restrict__ wsq,
                         ushort* __restrict__ WB) {
  int t = threadIdx.x;
  int lane = t & 63, wv = t >> 6;
  int k = blockIdx.x * 4 + wv;
  int d0 = lane * 4;
  float4 v = *(const float4*)&w[(size_t)k * DDIM + d0];
  float s = v.x * v.x + v.y * v.y + v.z * v.z + v.w * v.w;
  s = wred_sum(s);
  if (lane == 0) wsq[k] = s;
  float vv[4] = {v.x, v.y, v.z, v.w};
  union { ushort u[4]; uint2 q; } hh, mm;
#pragma unroll
  for (int q = 0; q < 4; ++q) {
    ushort h = f2bf(vv[q]);
    float r = vv[q] - bf2f(h);
    hh.u[q] = h;
    mm.u[q] = f2bf(r);
  }
  ushort* row = WB + (size_t)k * 768;
  *(uint2*)&row[d0] = hh.q;
  *(uint2*)&row[256 + d0] = hh.q;
  *(uint2*)&row[512 + d0] = mm.q;
}

// ---------------- x -> XS3 (3-way bf16 split) + xsq ----------------
__global__ __launch_bounds__(256) void k_xsplit(const float* __restrict__ x,
                                                ushort* __restrict__ XS3,
                                                float* __restrict__ xsq) {
  __shared__ __align__(16) ushort sl[32 * 776];
  __shared__ float sq[32 * 9];
  int t = threadIdx.x;
  int b = blockIdx.x >> 5, mt = blockIdx.x & 31;
  int m0 = mt * 32, mloc = t & 31, dgrp = t >> 5;
  const float* xb = x + (size_t)b * DDIM * 1024 + m0 + mloc;
  float s = 0.f;
#pragma unroll
  for (int jj = 0; jj < 8; ++jj) {
    int d0 = dgrp * 32 + jj * 4;
    float vv[4];
#pragma unroll
    for (int q = 0; q < 4; ++q) vv[q] = xb[(size_t)(d0 + q) * 1024];
    union { ushort u[4]; uint2 q; } hh, mi, lo;
#pragma unroll
    for (int q = 0; q < 4; ++q) {
      float v = vv[q];
      ushort h = f2bf(v);
      float r1 = v - bf2f(h);
      ushort m_ = f2bf(r1);
      float r2 = r1 - bf2f(m_);
      hh.u[q] = h; mi.u[q] = m_; lo.u[q] = f2bf(r2);
      s = fmaf(v, v, s);
    }
    int base = mloc * 776;
    *(uint2*)&sl[base + d0] = hh.q;
    *(uint2*)&sl[base + 256 + d0] = mi.q;
    *(uint2*)&sl[base + 512 + d0] = lo.q;
  }
  sq[mloc * 9 + dgrp] = s;
  __syncthreads();
  if (t < 32) {
    float ss = 0.f;
#pragma unroll
    for (int gq = 0; gq < 8; ++gq) ss += sq[t * 9 + gq];
    xsq[b * 1024 + m0 + t] = ss;
  }
  ushort* dst = XS3 + (size_t)(b * 1024 + m0) * 768;
#pragma unroll
  for (int p = 0; p < 12; ++p) {
    int idx = p * 256 + t;
    int row = idx / 96;
    int co = idx - row * 96;
    *(uint4*)&dst[(size_t)row * 768 + co * 8] = *(uint4*)&sl[row * 776 + co * 8];
  }
}

// ---------------- GEMM1 half: S[nloc][1024] = nd ; 2-phase dbuf pipeline ----------------
// 128n x 128k tile, 256 thr = 4 waves, K-step 64, 12 steps (hi*wh, mid*wh, hi*wm).
// Epilogue: nd + S store only (top2 moved to rowops2).
__global__ __launch_bounds__(256) void k_gemm1t(const ushort* __restrict__ XS3h,
                                                const ushort* __restrict__ WB,
                                                const float* __restrict__ wsq,
                                                const float* __restrict__ xsqh,
                                                float* __restrict__ S) {
  __shared__ __align__(16) ushort Asl[2][8192];
  __shared__ __align__(16) ushort Bsl[2][8192];
  __shared__ float xsl[128];
  __shared__ float wsl[128];
  int t = threadIdx.x;
  int kt = blockIdx.x;
  int n0 = blockIdx.y * 128;
  int k0 = kt * 128;
  int l = t & 63, wid = t >> 6;
  int wr = wid >> 1, wc = wid & 1;
  int hi = l >> 4, c = l & 15;

  if (t < 128) { xsl[t] = xsqh[n0 + t]; wsl[t] = wsq[k0 + t]; }

  f32x4 zero = {0.f, 0.f, 0.f, 0.f};
  f32x4 acc[4][4];
#pragma unroll
  for (int i = 0; i < 4; ++i)
#pragma unroll
    for (int j = 0; j < 4; ++j) acc[i][j] = zero;

  const char* XSb = (const char*)XS3h;
  const char* WBb = (const char*)WB;
  int lr = l >> 3;
  int lsw = ((l & 7) ^ lr) << 4;

#define STAGE(s_, b_)                                                              \
  {                                                                                \
    size_t bofs_ = (size_t)(s_) << 7;                                              \
    size_t aofs_ = (size_t)(((s_) < 8) ? (s_) : (s_) - 8) << 7;                    \
    char* Ad_ = (char*)Asl + (b_) * 16384;                                         \
    char* Bd_ = (char*)Bsl + (b_) * 16384;                                         \
    _Pragma("unroll")                                                              \
    for (int q_ = 0; q_ < 4; ++q_) {                                               \
      int seg_ = wid * 32 + q_ * 8;                                                \
      GLOAD_LDS16(XSb + (size_t)(n0 + seg_ + lr) * 1536 + aofs_ + lsw,             \
                  Ad_ + seg_ * 128);                                               \
      GLOAD_LDS16(WBb + (size_t)(k0 + seg_ + lr) * 1536 + bofs_ + lsw,             \
                  Bd_ + seg_ * 128);                                               \
    }                                                                              \
  }

  STAGE(0, 0);
  asm volatile("s_waitcnt vmcnt(0)" ::: "memory");
  __builtin_amdgcn_s_barrier();
  __builtin_amdgcn_sched_barrier(0);

  int buf = 0;
  for (int s = 0; s < 12; ++s) {
    if (s < 11) STAGE(s + 1, buf ^ 1);
    const ushort* Ab = &Asl[buf][0];
    const ushort* Bb = &Bsl[buf][0];
#pragma unroll
    for (int kk = 0; kk < 2; ++kk) {
      bf16x8 af[4], bg[4];
#pragma unroll
      for (int i = 0; i < 4; ++i) {
        int row = wr * 64 + i * 16 + c;
        int ch = (kk * 4 + hi) ^ (row & 7);
        af[i] = *(const bf16x8*)&Ab[row * 64 + ch * 8];
      }
#pragma unroll
      for (int j = 0; j < 4; ++j) {
        int row = wc * 64 + j * 16 + c;
        int ch = (kk * 4 + hi) ^ (row & 7);
        bg[j] = *(const bf16x8*)&Bb[row * 64 + ch * 8];
      }
#pragma unroll
      for (int i = 0; i < 4; ++i)
#pragma unroll
        for (int j = 0; j < 4; ++j)
          acc[i][j] = __builtin_amdgcn_mfma_f32_16x16x32_bf16(af[i], bg[j], acc[i][j], 0, 0, 0);
    }
    asm volatile("s_waitcnt vmcnt(0)" ::: "memory");
    __builtin_amdgcn_s_barrier();
    buf ^= 1;
  }
#undef STAGE

  // epilogue: nd + S store
#pragma unroll
  for (int i = 0; i < 4; ++i) {
#pragma unroll
    for (int r = 0; r < 4; ++r) {
      int nl = wr * 64 + i * 16 + hi * 4 + r;
      float xs = xsl[nl];
#pragma unroll
      for (int j = 0; j < 4; ++j) {
        int kl = wc * 64 + j * 16 + c;
        float nd = fmaf(2.f, acc[i][j][r], -(xs + wsl[kl]));
        S[(size_t)(n0 + nl) * 1024 + k0 + kl] = nd;
      }
    }
  }
}

// ---------------- streaming softmax in place + top2(nd+gumbel) (per half) ----------------
__global__ __launch_bounds__(256) void k_rowops2(float* __restrict__ S,
                                                 const float* __restrict__ Gh,
                                                 float* __restrict__ benth,
                                                 int* __restrict__ t2igh) {
  __shared__ float went[4];
  int t = threadIdx.x;
  int l = t & 63, wv = t >> 6;
  int n = blockIdx.x * 4 + wv;
  float* row = S + ((size_t)n << 10);
  const float* grow = Gh + ((size_t)n << 10);
  float v[16];
  float mx = -3.0e38f;
  float v1 = -3.0e38f, v2 = -3.0e38f;
  int i1 = 0x7fffffff, i2 = 0x7fffffff;
#pragma unroll
  for (int j = 0; j < 4; ++j) {
    float4 a = *(const float4*)&row[j * 256 + l * 4];
    float4 gg = *(const float4*)&grow[j * 256 + l * 4];
    float av[4] = {a.x, a.y, a.z, a.w};
    float gv[4] = {gg.x, gg.y, gg.z, gg.w};
#pragma unroll
    for (int q = 0; q < 4; ++q) {
      v[j * 4 + q] = av[q];
      mx = fmaxf(mx, av[q]);
      float sc = av[q] + gv[q];
      int kk = j * 256 + l * 4 + q;
      if (sc > v1 || (sc == v1 && kk < i1)) { v2 = v1; i2 = i1; v1 = sc; i1 = kk; }
      else if (sc > v2 || (sc == v2 && kk < i2)) { v2 = sc; i2 = kk; }
    }
  }
#pragma unroll
  for (int off = 1; off < 64; off <<= 1) {
    mx = fmaxf(mx, __shfl_xor(mx, off));
    float ov1 = __shfl_xor(v1, off), ov2 = __shfl_xor(v2, off);
    int oi1 = __shfl_xor(i1, off), oi2 = __shfl_xor(i2, off);
    bool fB = (ov1 > v1) || (ov1 == v1 && oi1 < i1);
    float nv1 = fB ? ov1 : v1; int ni1 = fB ? oi1 : i1;
    float ca = fB ? v1 : ov1;  int cia = fB ? i1 : oi1;
    float cb = fB ? ov2 : v2;  int cib = fB ? oi2 : i2;
    bool sB = (cb > ca) || (cb == ca && cib < cia);
    v1 = nv1; i1 = ni1;
    v2 = sB ? cb : ca; i2 = sB ? cib : cia;
  }
  if (l == 0) { t2igh[n * 2] = i1; t2igh[n * 2 + 1] = i2; }

  float M = 2.f * mx;
  float e[16]; float ps = 0.f;
#pragma unroll
  for (int u = 0; u < 16; ++u) { e[u] = __expf(fmaf(2.f, v[u], -M)); ps += e[u]; }
  ps = wred_sum(ps);
  float inv = 1.f / ps;
  float ent = 0.f;
#pragma unroll
  for (int j = 0; j < 4; ++j) {
    float4 o;
    float s0 = e[j * 4 + 0] * inv, s1 = e[j * 4 + 1] * inv;
    float s2 = e[j * 4 + 2] * inv, s3 = e[j * 4 + 3] * inv;
    ent += s0 * __logf(fmaxf(s0, 1e-8f)) + s1 * __logf(fmaxf(s1, 1e-8f));
    ent += s2 * __logf(fmaxf(s2, 1e-8f)) + s3 * __logf(fmaxf(s3, 1e-8f));
    o.x = s0; o.y = s1; o.z = s2; o.w = s3;
    *(float4*)&row[j * 256 + l * 4] = o;
  }
  ent = wred_sum(ent);
  if (l == 0) went[wv] = ent;
  __syncthreads();
  if (t == 0) benth[blockIdx.x] = went[0] + went[1] + went[2] + went[3];
}

// ---------------- transpose soft fp32 [16384][1024] -> softT panel bf16 [1024][16384] ----------------
__global__ void k_transpose2(const float* __restrict__ soft, ushort* __restrict__ sTp) {
  __shared__ ushort lds[64 * 65];
  int t = threadIdx.x;
  int ktile = blockIdx.x & 15, nt = blockIdx.x >> 4;
  int n0 = nt * 64, k0 = ktile * 64;
#pragma unroll
  for (int p = 0; p < 2; ++p) {
    int row = p * 32 + (t >> 3);
    int c8 = (t & 7) * 8;
    float4 a = *(const float4*)&soft[(size_t)(n0 + row) * 1024 + k0 + c8];
    float4 b = *(const float4*)&soft[(size_t)(n0 + row) * 1024 + k0 + c8 + 4];
    ushort* d = &lds[row * 65 + c8];
    d[0] = f2bf(a.x); d[1] = f2bf(a.y); d[2] = f2bf(a.z); d[3] = f2bf(a.w);
    d[4] = f2bf(b.x); d[5] = f2bf(b.y); d[6] = f2bf(b.z); d[7] = f2bf(b.w);
  }
  __syncthreads();
#pragma unroll
  for (int p = 0; p < 2; ++p) {
    int krow = p * 32 + (t >> 3);
    int nc8 = (t & 7) * 8;
    uint* dst = (uint*)&sTp[(size_t)(k0 + krow) * NHALF + n0 + nc8];
#pragma unroll
    for (int j = 0; j < 4; ++j) {
      uint lo = lds[(nc8 + 2 * j) * 65 + krow];
      uint hh = lds[(nc8 + 2 * j + 1) * 65 + krow];
      dst[j] = lo | (hh << 16);
    }
  }
}

// ---------------- exact argmax refinement ----------------
__global__ __launch_bounds__(256) void k_refine(const ushort* __restrict__ XS3,
                                                const float* __restrict__ w,
                                                const float* __restrict__ wsq,
                                                const float* __restrict__ xsq,
                                                const float* __restrict__ G,
                                                const int* __restrict__ t2ig,
                                                int* __restrict__ idxArr,
                                                float* __restrict__ hcnt) {
  int t = threadIdx.x;
  int l = t & 63, wv = t >> 6;
  int base = blockIdx.x * 64 + wv * 16;
  int d0 = l * 4;
  for (int rr = 0; rr < 16; ++rr) {
    int n = base + rr;
    const ushort* p = XS3 + (size_t)n * 768;
    union { uint2 q; ushort u[4]; } ha, ma, la;
    ha.q = *(const uint2*)&p[d0];
    ma.q = *(const uint2*)&p[256 + d0];
    la.q = *(const uint2*)&p[512 + d0];
    float xv[4];
#pragma unroll
    for (int q = 0; q < 4; ++q) xv[q] = bf2f(ha.u[q]) + bf2f(ma.u[q]) + bf2f(la.u[q]);
    float xs = xsq[n];
    int ia = t2ig[n * 2], ib = t2ig[n * 2 + 1];
    float sc[2];
    int ids[2] = {ia, ib};
#pragma unroll
    for (int cdd = 0; cdd < 2; ++cdd) {
      int id = ids[cdd];
      const float* wr = w + (size_t)id * DDIM;
      float4 wv4 = *(const float4*)&wr[d0];
      float d = xv[0] * wv4.x + xv[1] * wv4.y + xv[2] * wv4.z + xv[3] * wv4.w;
      d = wred_sum(d);
      sc[cdd] = fmaf(2.f, d, -xs) - wsq[id] + G[((size_t)n << 10) + id];
    }
    int win = (sc[1] > sc[0] || (sc[1] == sc[0] && ib < ia)) ? ib : ia;
    if (l == 0) {
      idxArr[n] = win;
      atomicAdd(&hcnt[win], 1.f);
    }
  }
}

// ---------------- quantized output ----------------
__global__ void k_quant(const float* __restrict__ w, const int* __restrict__ idxArr,
                        float* __restrict__ outQ) {
  int n = blockIdx.x * 256 + threadIdx.x;
  int b = n >> 10, m = n & 1023;
  int id = idxArr[n];
  const float* wr = w + (size_t)id * DDIM;
  float* o = outQ + (size_t)b * DDIM * 1024 + m;
#pragma unroll 4
  for (int d = 0; d < DDIM; ++d) o[(size_t)d * 1024] = wr[d];
}

// ---------------- GEMM2 (MFMA bf16): dw = soft^T x ; B staged from fp32 x ----------------
__global__ __launch_bounds__(512) void k_gemm2_mfma(const ushort* __restrict__ sT0,
                                                    const ushort* __restrict__ sT1,
                                                    const float* __restrict__ x,
                                                    float* __restrict__ P) {
  __shared__ __align__(16) ushort Abuf[256 * 72];
  __shared__ __align__(16) ushort Bbuf[128 * 72];
  int t = threadIdx.x;
  int bid = blockIdx.x;
  int kt = bid & 3, dt = (bid >> 2) & 1, ns = bid >> 3;
  int k0 = kt * 256, d0 = dt * 128;
  int l = t & 63, wv = t >> 6;
  int wk = wv >> 1, wd = wv & 1;
  const ushort* Abase = (ns < 16) ? sT0 : sT1;
  size_t nloc0 = (size_t)(ns & 15) * 1024;
  f32x4 zero = {0.f, 0.f, 0.f, 0.f};
  f32x4 acc[4][4];
#pragma unroll
  for (int i = 0; i < 4; ++i)
#pragma unroll
    for (int j = 0; j < 4; ++j) acc[i][j] = zero;

  int colv = (t & 7) * 8;
  int rbase = t >> 3;
  for (int s = 0; s < 16; ++s) {
#pragma unroll
    for (int p = 0; p < 4; ++p) {
      int row = p * 64 + rbase;
      const uint* ap = (const uint*)(Abase + (size_t)(k0 + row) * NHALF + nloc0 + s * 64 + colv);
      uint4 v; v.x = ap[0]; v.y = ap[1]; v.z = ap[2]; v.w = ap[3];
      *(uint4*)&Abuf[row * 72 + colv] = v;
    }
#pragma unroll
    for (int p = 0; p < 2; ++p) {
      int row = p * 64 + rbase;
      const float* xp = &x[((size_t)ns * DDIM + d0 + row) * 1024 + s * 64 + colv];
      float4 a = *(const float4*)xp;
      float4 b = *(const float4*)(xp + 4);
      union { ushort u[8]; uint4 q; } pk;
      pk.u[0] = f2bf(a.x); pk.u[1] = f2bf(a.y); pk.u[2] = f2bf(a.z); pk.u[3] = f2bf(a.w);
      pk.u[4] = f2bf(b.x); pk.u[5] = f2bf(b.y); pk.u[6] = f2bf(b.z); pk.u[7] = f2bf(b.w);
      *(uint4*)&Bbuf[row * 72 + colv] = pk.q;
    }
    __syncthreads();
    bf16x8 af[4], bfr[4];
#pragma unroll
    for (int nb2 = 0; nb2 < 2; ++nb2) {
#pragma unroll
      for (int sub = 0; sub < 4; ++sub) {
        af[sub] = *(const bf16x8*)&Abuf[(wk * 64 + sub * 16 + (l & 15)) * 72 + nb2 * 32 + (l >> 4) * 8];
        bfr[sub] = *(const bf16x8*)&Bbuf[(wd * 64 + sub * 16 + (l & 15)) * 72 + nb2 * 32 + (l >> 4) * 8];
      }
#pragma unroll
      for (int i = 0; i < 4; ++i)
#pragma unroll
        for (int j = 0; j < 4; ++j)
          acc[i][j] = __builtin_amdgcn_mfma_f32_16x16x32_bf16(af[i], bfr[j], acc[i][j], 0, 0, 0);
    }
    __syncthreads();
  }
  float* Pb = P + (size_t)ns * (KCB * DDIM);
#pragma unroll
  for (int i = 0; i < 4; ++i)
#pragma unroll
    for (int j = 0; j < 4; ++j) {
#pragma unroll
      for (int r = 0; r < 4; ++r) {
        int k = k0 + wk * 64 + i * 16 + (l >> 4) * 4 + r;
        int d = d0 + wd * 64 + j * 16 + (l & 15);
        Pb[(size_t)k * DDIM + d] = acc[i][j][r];
      }
    }
}

// ---------------- colsum over two softT panels ----------------
__global__ void k_colsum2(const ushort* __restrict__ sT0, const ushort* __restrict__ sT1,
                          float* __restrict__ colsum) {
  int k = blockIdx.x;
  int t = threadIdx.x;
  const uint* r0 = (const uint*)(sT0 + (size_t)k * NHALF);
  const uint* r1 = (const uint*)(sT1 + (size_t)k * NHALF);
  float s = 0.f;
#pragma unroll
  for (int cc = 0; cc < 8; ++cc) {
#pragma unroll
    for (int q = 0; q < 4; ++q) {
      uint a = r0[cc * 1024 + t * 4 + q];
      uint b = r1[cc * 1024 + t * 4 + q];
      s += bf2f((ushort)(a & 0xffffu)) + bf2f((ushort)(a >> 16));
      s += bf2f((ushort)(b & 0xffffu)) + bf2f((ushort)(b >> 16));
    }
  }
  s = wred_sum(s);
  __shared__ float ws4[4];
  if ((t & 63) == 0) ws4[t >> 6] = s;
  __syncthreads();
  if (t == 0) colsum[k] = ws4[0] + ws4[1] + ws4[2] + ws4[3];
}

// ---------------- finalize scalars, new_count ----------------
__global__ void k_final1(const float* __restrict__ ema_count, const float* __restrict__ colsum,
                         const float* __restrict__ hcnt, const float* __restrict__ bent,
                         float* __restrict__ ncnt, float* __restrict__ out) {
  __shared__ float red[1024];
  int t = threadIdx.x;
  const float onem = 1.0f - 0.99f;
  float nc = ema_count[t] * 0.99f + colsum[t] * onem;
  nc = (nc + 1e-5f) / (32768.0f + 1024.0f * 1e-5f) * 32768.0f;
  out[O_NCNT + t] = nc;
  ncnt[t] = nc;
  float s = 0.f;
  for (int i = t; i < 8192; i += 1024) s += bent[i];
  red[t] = s;
  __syncthreads();
  for (int off = 512; off > 0; off >>= 1) { if (t < off) red[t] += red[t + off]; __syncthreads(); }
  if (t == 0) out[O_LOSS] = 0.25f * (red[0] / 32768.0f);
  __syncthreads();
  float avg = hcnt[t] * (1.0f / 32768.0f);
  red[t] = avg * logf(avg + 1e-10f);
  __syncthreads();
  for (int off = 512; off > 0; off >>= 1) { if (t < off) red[t] += red[t + off]; __syncthreads(); }
  if (t == 0) out[O_PERP] = expf(-red[0]);
}

// ---------------- reduce dw partials + new_ema_weight & new_embedding ----------------
__global__ void k_reduce_final2(const float* __restrict__ P, const float* __restrict__ ema_w,
                                const float* __restrict__ ncnt, float* __restrict__ outEW,
                                float* __restrict__ outEMB) {
  int i = blockIdx.x * 256 + threadIdx.x;
  float s = 0.f;
#pragma unroll
  for (int ns = 0; ns < 32; ++ns) s += P[(size_t)ns * (KCB * DDIM) + i];
  float ew = ema_w[i] * 0.99f + s * 0.01f;
  outEW[i] = ew;
  outEMB[i] = ew / ncnt[i >> 8];
}

// ---------------- one-hot encodings (overwrites E scratch, last) ----------------
__global__ void k_onehot(const int* __restrict__ idxArr, float* __restrict__ E) {
  int gid = blockIdx.x * 256 + threadIdx.x;
  int n = gid >> 8;
  int k4 = (gid & 255) * 4;
  int id = idxArr[n];
  float2* E2 = (float2*)E;
  size_t base = ((size_t)n * KCB + k4) >> 1;
  float2 vA = {(float)(k4 == id), (float)(k4 + 1 == id)};
  float2 vB = {(float)(k4 + 2 == id), (float)(k4 + 3 == id)};
  E2[base] = vA;
  E2[base + 1] = vB;
}

extern "C" void kernel_launch(void* const* d_in, const int* in_sizes, int n_in,
                              void* d_out, int out_size, void* d_ws, size_t ws_size,
                              hipStream_t stream) {
  const float* x = (const float*)d_in[0];
  const float* w = (const float*)d_in[1];
  const float* ema_count = (const float*)d_in[2];
  const float* ema_w = (const float*)d_in[3];
  const float* g = (const float*)d_in[4];
  float* out = (float*)d_out;
  float* ws = (float*)d_ws;

  float* wsq    = ws + W_WSQ;
  float* xsq    = ws + W_XSQ;
  int*   idxArr = (int*)(ws + W_IDX);
  float* colsum = ws + W_COL;
  float* hcnt   = ws + W_HCNT;
  float* bent   = ws + W_BENT;
  float* ncnt   = ws + W_NCNT;
  int*   top2i  = (int*)(ws + W_T2I);
  ushort* WB    = (ushort*)(ws + W_WB);

  float* outQ = out + O_Q;
  float* outE = out + O_ENC;

  ushort* XS3    = (ushort*)(outE + E_XS3);     // 16B-aligned
  float*  Sslot  = outE + E_S;                  // 16B-aligned
  ushort* softT1 = (ushort*)(outE + E_XS3);     // overwrites XS3 after refine
  ushort* softT0 = (ushort*)outQ;               // Q region (4B-aligned: uint ops only)

  k_init<<<4, 256, 0, stream>>>(hcnt);
  k_wsplit<<<256, 256, 0, stream>>>(w, wsq, WB);
  k_xsplit<<<1024, 256, 0, stream>>>(x, XS3, xsq);
  // ---- half 0 (rows 0..16383) ----
  k_gemm1t<<<dim3(8, 128), 256, 0, stream>>>(XS3, WB, wsq, xsq, Sslot);
  k_rowops2<<<4096, 256, 0, stream>>>(Sslot, g, bent, top2i);
  k_transpose2<<<4096, 256, 0, stream>>>(Sslot, softT0);
  // ---- half 1 (rows 16384..32767) ----
  k_gemm1t<<<dim3(8, 128), 256, 0, stream>>>(XS3 + (size_t)NHALF * 768, WB,
                                             wsq, xsq + NHALF, Sslot);
  k_rowops2<<<4096, 256, 0, stream>>>(Sslot, g + (size_t)NHALF * 1024,
                                      bent + 4096, top2i + NHALF * 2);
  k_refine<<<512, 256, 0, stream>>>(XS3, w, wsq, xsq, g, top2i, idxArr, hcnt);
  k_transpose2<<<4096, 256, 0, stream>>>(Sslot, softT1);   // overwrites XS3 (refine done)
  k_colsum2<<<1024, 256, 0, stream>>>(softT0, softT1, colsum);
  k_gemm2_mfma<<<256, 512, 0, stream>>>(softT0, softT1, x, Sslot);  // P -> Sslot head
  k_final1<<<1, 1024, 0, stream>>>(ema_count, colsum, hcnt, bent, ncnt, out);
  k_reduce_final2<<<1024, 256, 0, stream>>>(Sslot, ema_w, ncnt, out + O_EMAW, out + O_EMB);
  k_quant<<<128, 256, 0, stream>>>(w, idxArr, outQ);       // overwrites softT0
  k_onehot<<<32768, 256, 0, stream>>>(idxArr, outE);       // overwrites all E scratch
}

// Round 10
// 359.607 us; speedup vs baseline: 3.9014x; 1.1196x over previous
//
#include <hip/hip_runtime.h>
#include <math.h>

// Problem constants
#define NROWS 32768   // B*H*W
#define KCB   1024
#define DDIM  256
#define NHALF 16384

// Output offsets (floats)
#define O_LOSS 0
#define O_Q    1
#define O_PERP 8388609
#define O_ENC  8388610
#define O_NCNT 41943042
#define O_EMAW 41944066
#define O_EMB  42206210

// E-region scratch (floats rel. outE; region = 33,554,432 floats):
//   XS3   @ 2          : bf16 [32768][768] (hi|mid|lo) = 12,582,912 floats (16B-aligned)
//   Sslot @ 12582914   : fp32 [16384][1024] nd values = 16,777,216 floats -> ends 29,360,130
//   softT1 aliases XS3 base (written after refine); P partials alias Sslot head.
#define E_XS3   2
#define E_S     12582914

// Workspace offsets (floats)
#define W_WSQ  0        // 1024
#define W_XSQ  1024     // 32768
#define W_IDX  33792    // 32768 (int)
#define W_COL  66560    // 1024
#define W_HCNT 67584    // 1024
#define W_BENT 68608    // 8192
#define W_NCNT 76800    // 1024
#define W_T2I  77824    // 65536 (int)
#define W_WB   143360   // 1024*256 ushorts = 131072 floats (w_hi only)
#define W_MROW 274432   // 32768
#define W_IROW 307200   // 32768
// total 339,968 floats = 1.36 MB

typedef __attribute__((ext_vector_type(8))) short bf16x8;
typedef __attribute__((ext_vector_type(4))) float f32x4;

#define GLOAD_LDS16(g, l) __builtin_amdgcn_global_load_lds( \
    (const __attribute__((address_space(1))) unsigned int*)(g), \
    (__attribute__((address_space(3))) unsigned int*)(l), 16, 0, 0)

__device__ __forceinline__ float wred_sum(float v) {
#pragma unroll
  for (int off = 32; off > 0; off >>= 1) v += __shfl_xor(v, off);
  return v;
}
__device__ __forceinline__ ushort f2bf(float f) {
  union { float f; unsigned u; } c; c.f = f;
  unsigned u = c.u;
  return (ushort)((u + 0x7fffu + ((u >> 16) & 1u)) >> 16);  // RNE
}
__device__ __forceinline__ float bf2f(ushort h) {
  union { unsigned u; float f; } c; c.u = ((unsigned)h) << 16;
  return c.f;
}

// ---------------- init ----------------
__global__ void k_init(float* __restrict__ hcnt) {
  int i = blockIdx.x * 256 + threadIdx.x;
  if (i < 1024) hcnt[i] = 0.f;
}

// ---------------- w -> wsq + WB [k][256] = w_hi ----------------
__global__ void k_wsplit(const float* __restrict__ w, float* __restrict__ wsq,
                         ushort* __restrict__ WB) {
  int t = threadIdx.x;
  int lane = t & 63, wv = t >> 6;
  int k = blockIdx.x * 4 + wv;
  int d0 = lane * 4;
  float4 v = *(const float4*)&w[(size_t)k * DDIM + d0];
  float s = v.x * v.x + v.y * v.y + v.z * v.z + v.w * v.w;
  s = wred_sum(s);
  if (lane == 0) wsq[k] = s;
  float vv[4] = {v.x, v.y, v.z, v.w};
  union { ushort u[4]; uint2 q; } hh;
#pragma unroll
  for (int q = 0; q < 4; ++q) hh.u[q] = f2bf(vv[q]);
  *(uint2*)&WB[(size_t)k * 256 + d0] = hh.q;
}

// ---------------- x -> XS3 (3-way bf16 split) + xsq ----------------
__global__ __launch_bounds__(256) void k_xsplit(const float* __restrict__ x,
                                                ushort* __restrict__ XS3,
                                                float* __restrict__ xsq) {
  __shared__ __align__(16) ushort sl[32 * 776];
  __shared__ float sq[32 * 9];
  int t = threadIdx.x;
  int b = blockIdx.x >> 5, mt = blockIdx.x & 31;
  int m0 = mt * 32, mloc = t & 31, dgrp = t >> 5;
  const float* xb = x + (size_t)b * DDIM * 1024 + m0 + mloc;
  float s = 0.f;
#pragma unroll
  for (int jj = 0; jj < 8; ++jj) {
    int d0 = dgrp * 32 + jj * 4;
    float vv[4];
#pragma unroll
    for (int q = 0; q < 4; ++q) vv[q] = xb[(size_t)(d0 + q) * 1024];
    union { ushort u[4]; uint2 q; } hh, mi, lo;
#pragma unroll
    for (int q = 0; q < 4; ++q) {
      float v = vv[q];
      ushort h = f2bf(v);
      float r1 = v - bf2f(h);
      ushort m_ = f2bf(r1);
      float r2 = r1 - bf2f(m_);
      hh.u[q] = h; mi.u[q] = m_; lo.u[q] = f2bf(r2);
      s = fmaf(v, v, s);
    }
    int base = mloc * 776;
    *(uint2*)&sl[base + d0] = hh.q;
    *(uint2*)&sl[base + 256 + d0] = mi.q;
    *(uint2*)&sl[base + 512 + d0] = lo.q;
  }
  sq[mloc * 9 + dgrp] = s;
  __syncthreads();
  if (t < 32) {
    float ss = 0.f;
#pragma unroll
    for (int gq = 0; gq < 8; ++gq) ss += sq[t * 9 + gq];
    xsq[b * 1024 + m0 + t] = ss;
  }
  ushort* dst = XS3 + (size_t)(b * 1024 + m0) * 768;
#pragma unroll
  for (int p = 0; p < 12; ++p) {
    int idx = p * 256 + t;
    int row = idx / 96;
    int co = idx - row * 96;
    *(uint4*)&dst[(size_t)row * 768 + co * 8] = *(uint4*)&sl[row * 776 + co * 8];
  }
}

// ---------------- GEMM1 half: S[nloc][1024] = nd ; 2-phase dbuf, 8 K-steps ----------------
// s = (x_hi + x_mid) . w_hi : steps 0-3 A=x_hi, steps 4-7 A=x_mid, B=w_hi both.
__global__ __launch_bounds__(256) void k_gemm1t(const ushort* __restrict__ XS3h,
                                                const ushort* __restrict__ WB,
                                                const float* __restrict__ wsq,
                                                const float* __restrict__ xsqh,
                                                float* __restrict__ S) {
  __shared__ __align__(16) ushort Asl[2][8192];
  __shared__ __align__(16) ushort Bsl[2][8192];
  __shared__ float xsl[128];
  __shared__ float wsl[128];
  int t = threadIdx.x;
  int kt = blockIdx.x;
  int n0 = blockIdx.y * 128;
  int k0 = kt * 128;
  int l = t & 63, wid = t >> 6;
  int wr = wid >> 1, wc = wid & 1;
  int hi = l >> 4, c = l & 15;

  if (t < 128) { xsl[t] = xsqh[n0 + t]; wsl[t] = wsq[k0 + t]; }

  f32x4 zero = {0.f, 0.f, 0.f, 0.f};
  f32x4 acc[4][4];
#pragma unroll
  for (int i = 0; i < 4; ++i)
#pragma unroll
    for (int j = 0; j < 4; ++j) acc[i][j] = zero;

  const char* XSb = (const char*)XS3h;
  const char* WBb = (const char*)WB;
  int lr = l >> 3;
  int lsw = ((l & 7) ^ lr) << 4;

#define STAGE(s_, b_)                                                              \
  {                                                                                \
    size_t bofs_ = (size_t)((s_) & 3) << 7;                                        \
    size_t aofs_ = ((s_) < 4) ? ((size_t)(s_) << 7)                                \
                              : (size_t)(512 + (((s_) - 4) << 7));                 \
    char* Ad_ = (char*)Asl + (b_) * 16384;                                         \
    char* Bd_ = (char*)Bsl + (b_) * 16384;                                         \
    _Pragma("unroll")                                                              \
    for (int q_ = 0; q_ < 4; ++q_) {                                               \
      int seg_ = wid * 32 + q_ * 8;                                                \
      GLOAD_LDS16(XSb + (size_t)(n0 + seg_ + lr) * 1536 + aofs_ + lsw,             \
                  Ad_ + seg_ * 128);                                               \
      GLOAD_LDS16(WBb + (size_t)(k0 + seg_ + lr) * 512 + bofs_ + lsw,              \
                  Bd_ + seg_ * 128);                                               \
    }                                                                              \
  }

  STAGE(0, 0);
  asm volatile("s_waitcnt vmcnt(0)" ::: "memory");
  __builtin_amdgcn_s_barrier();
  __builtin_amdgcn_sched_barrier(0);

  int buf = 0;
  for (int s = 0; s < 8; ++s) {
    if (s < 7) STAGE(s + 1, buf ^ 1);
    const ushort* Ab = &Asl[buf][0];
    const ushort* Bb = &Bsl[buf][0];
#pragma unroll
    for (int kk = 0; kk < 2; ++kk) {
      bf16x8 af[4], bg[4];
#pragma unroll
      for (int i = 0; i < 4; ++i) {
        int row = wr * 64 + i * 16 + c;
        int ch = (kk * 4 + hi) ^ (row & 7);
        af[i] = *(const bf16x8*)&Ab[row * 64 + ch * 8];
      }
#pragma unroll
      for (int j = 0; j < 4; ++j) {
        int row = wc * 64 + j * 16 + c;
        int ch = (kk * 4 + hi) ^ (row & 7);
        bg[j] = *(const bf16x8*)&Bb[row * 64 + ch * 8];
      }
#pragma unroll
      for (int i = 0; i < 4; ++i)
#pragma unroll
        for (int j = 0; j < 4; ++j)
          acc[i][j] = __builtin_amdgcn_mfma_f32_16x16x32_bf16(af[i], bg[j], acc[i][j], 0, 0, 0);
    }
    asm volatile("s_waitcnt vmcnt(0)" ::: "memory");
    __builtin_amdgcn_s_barrier();
    buf ^= 1;
  }
#undef STAGE

  // epilogue: nd + S store
#pragma unroll
  for (int i = 0; i < 4; ++i) {
#pragma unroll
    for (int r = 0; r < 4; ++r) {
      int nl = wr * 64 + i * 16 + hi * 4 + r;
      float xs = xsl[nl];
#pragma unroll
      for (int j = 0; j < 4; ++j) {
        int kl = wc * 64 + j * 16 + c;
        float nd = fmaf(2.f, acc[i][j][r], -(xs + wsl[kl]));
        S[(size_t)(n0 + nl) * 1024 + k0 + kl] = nd;
      }
    }
  }
}

// ---------------- row stats: max, 1/sum, top2(nd+g), entropy (S read-only) ----------------
__global__ __launch_bounds__(256) void k_rowstat(const float* __restrict__ S,
                                                 const float* __restrict__ Gh,
                                                 float* __restrict__ Mrowh,
                                                 float* __restrict__ Irowh,
                                                 float* __restrict__ benth,
                                                 int* __restrict__ t2igh) {
  __shared__ float went[4];
  int t = threadIdx.x;
  int l = t & 63, wv = t >> 6;
  int n = blockIdx.x * 4 + wv;
  const float* row = S + ((size_t)n << 10);
  const float* grow = Gh + ((size_t)n << 10);
  float v[16];
  float mx = -3.0e38f;
  float v1 = -3.0e38f, v2 = -3.0e38f;
  int i1 = 0x7fffffff, i2 = 0x7fffffff;
#pragma unroll
  for (int j = 0; j < 4; ++j) {
    float4 a = *(const float4*)&row[j * 256 + l * 4];
    float4 gg = *(const float4*)&grow[j * 256 + l * 4];
    float av[4] = {a.x, a.y, a.z, a.w};
    float gv[4] = {gg.x, gg.y, gg.z, gg.w};
#pragma unroll
    for (int q = 0; q < 4; ++q) {
      v[j * 4 + q] = av[q];
      mx = fmaxf(mx, av[q]);
      float sc = av[q] + gv[q];
      int kk = j * 256 + l * 4 + q;
      if (sc > v1 || (sc == v1 && kk < i1)) { v2 = v1; i2 = i1; v1 = sc; i1 = kk; }
      else if (sc > v2 || (sc == v2 && kk < i2)) { v2 = sc; i2 = kk; }
    }
  }
#pragma unroll
  for (int off = 1; off < 64; off <<= 1) {
    mx = fmaxf(mx, __shfl_xor(mx, off));
    float ov1 = __shfl_xor(v1, off), ov2 = __shfl_xor(v2, off);
    int oi1 = __shfl_xor(i1, off), oi2 = __shfl_xor(i2, off);
    bool fB = (ov1 > v1) || (ov1 == v1 && oi1 < i1);
    float nv1 = fB ? ov1 : v1; int ni1 = fB ? oi1 : i1;
    float ca = fB ? v1 : ov1;  int cia = fB ? i1 : oi1;
    float cb = fB ? ov2 : v2;  int cib = fB ? oi2 : i2;
    bool sB = (cb > ca) || (cb == ca && cib < cia);
    v1 = nv1; i1 = ni1;
    v2 = sB ? cb : ca; i2 = sB ? cib : cia;
  }
  float M = 2.f * mx;
  float e[16]; float ps = 0.f;
#pragma unroll
  for (int u = 0; u < 16; ++u) { e[u] = __expf(fmaf(2.f, v[u], -M)); ps += e[u]; }
  ps = wred_sum(ps);
  float inv = 1.f / ps;
  float ent = 0.f;
#pragma unroll
  for (int u = 0; u < 16; ++u) {
    float sfv = e[u] * inv;
    ent += sfv * __logf(fmaxf(sfv, 1e-8f));
  }
  ent = wred_sum(ent);
  if (l == 0) {
    t2igh[n * 2] = i1; t2igh[n * 2 + 1] = i2;
    Mrowh[n] = M; Irowh[n] = inv;
    went[wv] = ent;
  }
  __syncthreads();
  if (t == 0) benth[blockIdx.x] = went[0] + went[1] + went[2] + went[3];
}

// ---------------- soft recompute + bf16 transpose write: softT[k][nloc] ----------------
__global__ __launch_bounds__(512) void k_rowwrite(const float* __restrict__ S,
                                                  const float* __restrict__ Mrowh,
                                                  const float* __restrict__ Irowh,
                                                  ushort* __restrict__ sTp) {
  __shared__ ushort lds[64 * 65];
  __shared__ float Ml[64], Il[64];
  int t = threadIdx.x;
  int n0 = blockIdx.x * 64;
  if (t < 64) { Ml[t] = Mrowh[n0 + t]; Il[t] = Irowh[n0 + t]; }
  __syncthreads();
  for (int kt = 0; kt < 16; ++kt) {
    int k0 = kt * 64;
    int row = t >> 3, c8 = (t & 7) * 8;
    float M = Ml[row], inv = Il[row];
    const float* sp = &S[(size_t)(n0 + row) * 1024 + k0 + c8];
    float4 a = *(const float4*)sp;
    float4 b = *(const float4*)(sp + 4);
    float sv[8] = {a.x, a.y, a.z, a.w, b.x, b.y, b.z, b.w};
    ushort* d = &lds[row * 65 + c8];
#pragma unroll
    for (int j = 0; j < 8; ++j)
      d[j] = f2bf(__expf(fmaf(2.f, sv[j], -M)) * inv);
    __syncthreads();
    int krow = t >> 3, nc8 = (t & 7) * 8;
    uint* dst = (uint*)&sTp[(size_t)(k0 + krow) * NHALF + n0 + nc8];
#pragma unroll
    for (int j = 0; j < 4; ++j) {
      uint lo = lds[(nc8 + 2 * j) * 65 + krow];
      uint hh = lds[(nc8 + 2 * j + 1) * 65 + krow];
      dst[j] = lo | (hh << 16);
    }
    __syncthreads();
  }
}

// ---------------- exact argmax refinement ----------------
__global__ __launch_bounds__(256) void k_refine(const ushort* __restrict__ XS3,
                                                const float* __restrict__ w,
                                                const float* __restrict__ wsq,
                                                const float* __restrict__ xsq,
                                                const float* __restrict__ G,
                                                const int* __restrict__ t2ig,
                                                int* __restrict__ idxArr,
                                                float* __restrict__ hcnt) {
  int t = threadIdx.x;
  int l = t & 63, wv = t >> 6;
  int base = blockIdx.x * 64 + wv * 16;
  int d0 = l * 4;
  for (int rr = 0; rr < 16; ++rr) {
    int n = base + rr;
    const ushort* p = XS3 + (size_t)n * 768;
    union { uint2 q; ushort u[4]; } ha, ma, la;
    ha.q = *(const uint2*)&p[d0];
    ma.q = *(const uint2*)&p[256 + d0];
    la.q = *(const uint2*)&p[512 + d0];
    float xv[4];
#pragma unroll
    for (int q = 0; q < 4; ++q) xv[q] = bf2f(ha.u[q]) + bf2f(ma.u[q]) + bf2f(la.u[q]);
    float xs = xsq[n];
    int ia = t2ig[n * 2], ib = t2ig[n * 2 + 1];
    float sc[2];
    int ids[2] = {ia, ib};
#pragma unroll
    for (int cdd = 0; cdd < 2; ++cdd) {
      int id = ids[cdd];
      const float* wr = w + (size_t)id * DDIM;
      float4 wv4 = *(const float4*)&wr[d0];
      float d = xv[0] * wv4.x + xv[1] * wv4.y + xv[2] * wv4.z + xv[3] * wv4.w;
      d = wred_sum(d);
      sc[cdd] = fmaf(2.f, d, -xs) - wsq[id] + G[((size_t)n << 10) + id];
    }
    int win = (sc[1] > sc[0] || (sc[1] == sc[0] && ib < ia)) ? ib : ia;
    if (l == 0) {
      idxArr[n] = win;
      atomicAdd(&hcnt[win], 1.f);
    }
  }
}

// ---------------- quantized output ----------------
__global__ void k_quant(const float* __restrict__ w, const int* __restrict__ idxArr,
                        float* __restrict__ outQ) {
  int n = blockIdx.x * 256 + threadIdx.x;
  int b = n >> 10, m = n & 1023;
  int id = idxArr[n];
  const float* wr = w + (size_t)id * DDIM;
  float* o = outQ + (size_t)b * DDIM * 1024 + m;
#pragma unroll 4
  for (int d = 0; d < DDIM; ++d) o[(size_t)d * 1024] = wr[d];
}

// ---------------- GEMM2 (MFMA bf16): dw = soft^T x ; B staged from fp32 x ----------------
__global__ __launch_bounds__(512) void k_gemm2_mfma(const ushort* __restrict__ sT0,
                                                    const ushort* __restrict__ sT1,
                                                    const float* __restrict__ x,
                                                    float* __restrict__ P) {
  __shared__ __align__(16) ushort Abuf[256 * 72];
  __shared__ __align__(16) ushort Bbuf[128 * 72];
  int t = threadIdx.x;
  int bid = blockIdx.x;
  int kt = bid & 3, dt = (bid >> 2) & 1, ns = bid >> 3;
  int k0 = kt * 256, d0 = dt * 128;
  int l = t & 63, wv = t >> 6;
  int wk = wv >> 1, wd = wv & 1;
  const ushort* Abase = (ns < 16) ? sT0 : sT1;
  size_t nloc0 = (size_t)(ns & 15) * 1024;
  f32x4 zero = {0.f, 0.f, 0.f, 0.f};
  f32x4 acc[4][4];
#pragma unroll
  for (int i = 0; i < 4; ++i)
#pragma unroll
    for (int j = 0; j < 4; ++j) acc[i][j] = zero;

  int colv = (t & 7) * 8;
  int rbase = t >> 3;
  for (int s = 0; s < 16; ++s) {
#pragma unroll
    for (int p = 0; p < 4; ++p) {
      int row = p * 64 + rbase;
      const uint* ap = (const uint*)(Abase + (size_t)(k0 + row) * NHALF + nloc0 + s * 64 + colv);
      uint4 v; v.x = ap[0]; v.y = ap[1]; v.z = ap[2]; v.w = ap[3];
      *(uint4*)&Abuf[row * 72 + colv] = v;
    }
#pragma unroll
    for (int p = 0; p < 2; ++p) {
      int row = p * 64 + rbase;
      const float* xp = &x[((size_t)ns * DDIM + d0 + row) * 1024 + s * 64 + colv];
      float4 a = *(const float4*)xp;
      float4 b = *(const float4*)(xp + 4);
      union { ushort u[8]; uint4 q; } pk;
      pk.u[0] = f2bf(a.x); pk.u[1] = f2bf(a.y); pk.u[2] = f2bf(a.z); pk.u[3] = f2bf(a.w);
      pk.u[4] = f2bf(b.x); pk.u[5] = f2bf(b.y); pk.u[6] = f2bf(b.z); pk.u[7] = f2bf(b.w);
      *(uint4*)&Bbuf[row * 72 + colv] = pk.q;
    }
    __syncthreads();
    bf16x8 af[4], bfr[4];
#pragma unroll
    for (int nb2 = 0; nb2 < 2; ++nb2) {
#pragma unroll
      for (int sub = 0; sub < 4; ++sub) {
        af[sub] = *(const bf16x8*)&Abuf[(wk * 64 + sub * 16 + (l & 15)) * 72 + nb2 * 32 + (l >> 4) * 8];
        bfr[sub] = *(const bf16x8*)&Bbuf[(wd * 64 + sub * 16 + (l & 15)) * 72 + nb2 * 32 + (l >> 4) * 8];
      }
#pragma unroll
      for (int i = 0; i < 4; ++i)
#pragma unroll
        for (int j = 0; j < 4; ++j)
          acc[i][j] = __builtin_amdgcn_mfma_f32_16x16x32_bf16(af[i], bfr[j], acc[i][j], 0, 0, 0);
    }
    __syncthreads();
  }
  float* Pb = P + (size_t)ns * (KCB * DDIM);
#pragma unroll
  for (int i = 0; i < 4; ++i)
#pragma unroll
    for (int j = 0; j < 4; ++j) {
#pragma unroll
      for (int r = 0; r < 4; ++r) {
        int k = k0 + wk * 64 + i * 16 + (l >> 4) * 4 + r;
        int d = d0 + wd * 64 + j * 16 + (l & 15);
        Pb[(size_t)k * DDIM + d] = acc[i][j][r];
      }
    }
}

// ---------------- colsum over two softT panels ----------------
__global__ void k_colsum2(const ushort* __restrict__ sT0, const ushort* __restrict__ sT1,
                          float* __restrict__ colsum) {
  int k = blockIdx.x;
  int t = threadIdx.x;
  const uint* r0 = (const uint*)(sT0 + (size_t)k * NHALF);
  const uint* r1 = (const uint*)(sT1 + (size_t)k * NHALF);
  float s = 0.f;
#pragma unroll
  for (int cc = 0; cc < 8; ++cc) {
#pragma unroll
    for (int q = 0; q < 4; ++q) {
      uint a = r0[cc * 1024 + t * 4 + q];
      uint b = r1[cc * 1024 + t * 4 + q];
      s += bf2f((ushort)(a & 0xffffu)) + bf2f((ushort)(a >> 16));
      s += bf2f((ushort)(b & 0xffffu)) + bf2f((ushort)(b >> 16));
    }
  }
  s = wred_sum(s);
  __shared__ float ws4[4];
  if ((t & 63) == 0) ws4[t >> 6] = s;
  __syncthreads();
  if (t == 0) colsum[k] = ws4[0] + ws4[1] + ws4[2] + ws4[3];
}

// ---------------- finalize scalars, new_count ----------------
__global__ void k_final1(const float* __restrict__ ema_count, const float* __restrict__ colsum,
                         const float* __restrict__ hcnt, const float* __restrict__ bent,
                         float* __restrict__ ncnt, float* __restrict__ out) {
  __shared__ float red[1024];
  int t = threadIdx.x;
  const float onem = 1.0f - 0.99f;
  float nc = ema_count[t] * 0.99f + colsum[t] * onem;
  nc = (nc + 1e-5f) / (32768.0f + 1024.0f * 1e-5f) * 32768.0f;
  out[O_NCNT + t] = nc;
  ncnt[t] = nc;
  float s = 0.f;
  for (int i = t; i < 8192; i += 1024) s += bent[i];
  red[t] = s;
  __syncthreads();
  for (int off = 512; off > 0; off >>= 1) { if (t < off) red[t] += red[t + off]; __syncthreads(); }
  if (t == 0) out[O_LOSS] = 0.25f * (red[0] / 32768.0f);
  __syncthreads();
  float avg = hcnt[t] * (1.0f / 32768.0f);
  red[t] = avg * logf(avg + 1e-10f);
  __syncthreads();
  for (int off = 512; off > 0; off >>= 1) { if (t < off) red[t] += red[t + off]; __syncthreads(); }
  if (t == 0) out[O_PERP] = expf(-red[0]);
}

// ---------------- reduce dw partials + new_ema_weight & new_embedding ----------------
__global__ void k_reduce_final2(const float* __restrict__ P, const float* __restrict__ ema_w,
                                const float* __restrict__ ncnt, float* __restrict__ outEW,
                                float* __restrict__ outEMB) {
  int i = blockIdx.x * 256 + threadIdx.x;
  float s = 0.f;
#pragma unroll
  for (int ns = 0; ns < 32; ++ns) s += P[(size_t)ns * (KCB * DDIM) + i];
  float ew = ema_w[i] * 0.99f + s * 0.01f;
  outEW[i] = ew;
  outEMB[i] = ew / ncnt[i >> 8];
}

// ---------------- one-hot encodings (overwrites E scratch, last) ----------------
__global__ void k_onehot(const int* __restrict__ idxArr, float* __restrict__ E) {
  int gid = blockIdx.x * 256 + threadIdx.x;
  int n = gid >> 8;
  int k4 = (gid & 255) * 4;
  int id = idxArr[n];
  float2* E2 = (float2*)E;
  size_t base = ((size_t)n * KCB + k4) >> 1;
  float2 vA = {(float)(k4 == id), (float)(k4 + 1 == id)};
  float2 vB = {(float)(k4 + 2 == id), (float)(k4 + 3 == id)};
  E2[base] = vA;
  E2[base + 1] = vB;
}

extern "C" void kernel_launch(void* const* d_in, const int* in_sizes, int n_in,
                              void* d_out, int out_size, void* d_ws, size_t ws_size,
                              hipStream_t stream) {
  const float* x = (const float*)d_in[0];
  const float* w = (const float*)d_in[1];
  const float* ema_count = (const float*)d_in[2];
  const float* ema_w = (const float*)d_in[3];
  const float* g = (const float*)d_in[4];
  float* out = (float*)d_out;
  float* ws = (float*)d_ws;

  float* wsq    = ws + W_WSQ;
  float* xsq    = ws + W_XSQ;
  int*   idxArr = (int*)(ws + W_IDX);
  float* colsum = ws + W_COL;
  float* hcnt   = ws + W_HCNT;
  float* bent   = ws + W_BENT;
  float* ncnt   = ws + W_NCNT;
  int*   top2i  = (int*)(ws + W_T2I);
  ushort* WB    = (ushort*)(ws + W_WB);
  float* Mrow   = ws + W_MROW;
  float* Irow   = ws + W_IROW;

  float* outQ = out + O_Q;
  float* outE = out + O_ENC;

  ushort* XS3    = (ushort*)(outE + E_XS3);     // 16B-aligned
  float*  Sslot  = outE + E_S;                  // 16B-aligned
  ushort* softT1 = (ushort*)(outE + E_XS3);     // overwrites XS3 after refine
  ushort* softT0 = (ushort*)outQ;               // Q region (4B-aligned: uint ops only)

  k_init<<<4, 256, 0, stream>>>(hcnt);
  k_wsplit<<<256, 256, 0, stream>>>(w, wsq, WB);
  k_xsplit<<<1024, 256, 0, stream>>>(x, XS3, xsq);
  // ---- half 0 (rows 0..16383) ----
  k_gemm1t<<<dim3(8, 128), 256, 0, stream>>>(XS3, WB, wsq, xsq, Sslot);
  k_rowstat<<<4096, 256, 0, stream>>>(Sslot, g, Mrow, Irow, bent, top2i);
  k_rowwrite<<<256, 512, 0, stream>>>(Sslot, Mrow, Irow, softT0);
  // ---- half 1 (rows 16384..32767) ----
  k_gemm1t<<<dim3(8, 128), 256, 0, stream>>>(XS3 + (size_t)NHALF * 768, WB,
                                             wsq, xsq + NHALF, Sslot);
  k_rowstat<<<4096, 256, 0, stream>>>(Sslot, g + (size_t)NHALF * 1024,
                                      Mrow + NHALF, Irow + NHALF,
                                      bent + 4096, top2i + NHALF * 2);
  k_refine<<<512, 256, 0, stream>>>(XS3, w, wsq, xsq, g, top2i, idxArr, hcnt);
  k_rowwrite<<<256, 512, 0, stream>>>(Sslot, Mrow + NHALF, Irow + NHALF, softT1);
  k_colsum2<<<1024, 256, 0, stream>>>(softT0, softT1, colsum);
  k_gemm2_mfma<<<256, 512, 0, stream>>>(softT0, softT1, x, Sslot);  // P -> Sslot head
  k_final1<<<1, 1024, 0, stream>>>(ema_count, colsum, hcnt, bent, ncnt, out);
  k_reduce_final2<<<1024, 256, 0, stream>>>(Sslot, ema_w, ncnt, out + O_EMAW, out + O_EMB);
  k_quant<<<128, 256, 0, stream>>>(w, idxArr, outQ);       // overwrites softT0
  k_onehot<<<32768, 256, 0, stream>>>(idxArr, outE);       // overwrites all E scratch
}

// Round 11
// 330.894 us; speedup vs baseline: 4.2400x; 1.0868x over previous
//
#include <hip/hip_runtime.h>
#include <math.h>

// Problem constants
#define NROWS 32768   // B*H*W
#define KCB   1024
#define DDIM  256
#define NHALF 16384

// Output offsets (floats)
#define O_LOSS 0
#define O_Q    1
#define O_PERP 8388609
#define O_ENC  8388610
#define O_NCNT 41943042
#define O_EMAW 41944066
#define O_EMB  42206210

// E-region scratch (floats rel. outE; region = 33,554,432 floats):
//   XS3   @ 2          : bf16 [32768][768] (hi|mid|lo) = 12,582,912 floats (16B-aligned)
//   Sslot @ 12582914   : fp32 [16384][1024] nd values = 16,777,216 floats -> ends 29,360,130
//   softT1 aliases XS3 base (written after refine); P partials alias Sslot head.
#define E_XS3   2
#define E_S     12582914

// Workspace offsets (floats)
#define W_WSQ  0        // 1024
#define W_XSQ  1024     // 32768
#define W_IDX  33792    // 32768 (int)
#define W_COL  66560    // 1024
#define W_HCNT 67584    // 1024
#define W_BENT 68608    // 8192
#define W_NCNT 76800    // 1024
#define W_T2I  77824    // 65536 (int)
#define W_WB   143360   // 1024*256 ushorts = 131072 floats (w_hi only)
#define W_MROW 274432   // 32768
#define W_IROW 307200   // 32768

typedef __attribute__((ext_vector_type(8))) short bf16x8;
typedef __attribute__((ext_vector_type(4))) float f32x4;

#define GLOAD_LDS16(g, l) __builtin_amdgcn_global_load_lds( \
    (const __attribute__((address_space(1))) unsigned int*)(g), \
    (__attribute__((address_space(3))) unsigned int*)(l), 16, 0, 0)

__device__ __forceinline__ float wred_sum(float v) {
#pragma unroll
  for (int off = 32; off > 0; off >>= 1) v += __shfl_xor(v, off);
  return v;
}
__device__ __forceinline__ ushort f2bf(float f) {
  union { float f; unsigned u; } c; c.f = f;
  unsigned u = c.u;
  return (ushort)((u + 0x7fffu + ((u >> 16) & 1u)) >> 16);  // RNE
}
__device__ __forceinline__ float bf2f(ushort h) {
  union { unsigned u; float f; } c; c.u = ((unsigned)h) << 16;
  return c.f;
}

// ---------------- init ----------------
__global__ void k_init(float* __restrict__ hcnt) {
  int i = blockIdx.x * 256 + threadIdx.x;
  if (i < 1024) hcnt[i] = 0.f;
}

// ---------------- w -> wsq + WB [k][256] = w_hi ----------------
__global__ void k_wsplit(const float* __restrict__ w, float* __restrict__ wsq,
                         ushort* __restrict__ WB) {
  int t = threadIdx.x;
  int lane = t & 63, wv = t >> 6;
  int k = blockIdx.x * 4 + wv;
  int d0 = lane * 4;
  float4 v = *(const float4*)&w[(size_t)k * DDIM + d0];
  float s = v.x * v.x + v.y * v.y + v.z * v.z + v.w * v.w;
  s = wred_sum(s);
  if (lane == 0) wsq[k] = s;
  float vv[4] = {v.x, v.y, v.z, v.w};
  union { ushort u[4]; uint2 q; } hh;
#pragma unroll
  for (int q = 0; q < 4; ++q) hh.u[q] = f2bf(vv[q]);
  *(uint2*)&WB[(size_t)k * 256 + d0] = hh.q;
}

// ---------------- x -> XS3 (3-way bf16 split) + xsq ----------------
__global__ __launch_bounds__(256) void k_xsplit(const float* __restrict__ x,
                                                ushort* __restrict__ XS3,
                                                float* __restrict__ xsq) {
  __shared__ __align__(16) ushort sl[32 * 776];
  __shared__ float sq[32 * 9];
  int t = threadIdx.x;
  int b = blockIdx.x >> 5, mt = blockIdx.x & 31;
  int m0 = mt * 32, mloc = t & 31, dgrp = t >> 5;
  const float* xb = x + (size_t)b * DDIM * 1024 + m0 + mloc;
  float s = 0.f;
#pragma unroll
  for (int jj = 0; jj < 8; ++jj) {
    int d0 = dgrp * 32 + jj * 4;
    float vv[4];
#pragma unroll
    for (int q = 0; q < 4; ++q) vv[q] = xb[(size_t)(d0 + q) * 1024];
    union { ushort u[4]; uint2 q; } hh, mi, lo;
#pragma unroll
    for (int q = 0; q < 4; ++q) {
      float v = vv[q];
      ushort h = f2bf(v);
      float r1 = v - bf2f(h);
      ushort m_ = f2bf(r1);
      float r2 = r1 - bf2f(m_);
      hh.u[q] = h; mi.u[q] = m_; lo.u[q] = f2bf(r2);
      s = fmaf(v, v, s);
    }
    int base = mloc * 776;
    *(uint2*)&sl[base + d0] = hh.q;
    *(uint2*)&sl[base + 256 + d0] = mi.q;
    *(uint2*)&sl[base + 512 + d0] = lo.q;
  }
  sq[mloc * 9 + dgrp] = s;
  __syncthreads();
  if (t < 32) {
    float ss = 0.f;
#pragma unroll
    for (int gq = 0; gq < 8; ++gq) ss += sq[t * 9 + gq];
    xsq[b * 1024 + m0 + t] = ss;
  }
  ushort* dst = XS3 + (size_t)(b * 1024 + m0) * 768;
#pragma unroll
  for (int p = 0; p < 12; ++p) {
    int idx = p * 256 + t;
    int row = idx / 96;
    int co = idx - row * 96;
    *(uint4*)&dst[(size_t)row * 768 + co * 8] = *(uint4*)&sl[row * 776 + co * 8];
  }
}

// ---------------- GEMM1 half: S[nloc][1024] = nd ; 2-phase dbuf, 8 K-steps ----------------
// XCD-chunked swizzle: each XCD owns 16 contiguous n-tiles x all kt (A-tiles L2-resident).
__global__ __launch_bounds__(256) void k_gemm1t(const ushort* __restrict__ XS3h,
                                                const ushort* __restrict__ WB,
                                                const float* __restrict__ wsq,
                                                const float* __restrict__ xsqh,
                                                float* __restrict__ S) {
  __shared__ __align__(16) ushort Asl[2][8192];
  __shared__ __align__(16) ushort Bsl[2][8192];
  __shared__ float xsl[128];
  __shared__ float wsl[128];
  int t = threadIdx.x;
  int h = blockIdx.x;                 // 0..1023
  int xcd = h & 7, seq = h >> 3;      // round-robin XCD assumption (perf-only)
  int kt = seq & 7;
  int nt = xcd * 16 + (seq >> 3);
  int n0 = nt * 128;
  int k0 = kt * 128;
  int l = t & 63, wid = t >> 6;
  int wr = wid >> 1, wc = wid & 1;
  int hi = l >> 4, c = l & 15;

  if (t < 128) { xsl[t] = xsqh[n0 + t]; wsl[t] = wsq[k0 + t]; }

  f32x4 zero = {0.f, 0.f, 0.f, 0.f};
  f32x4 acc[4][4];
#pragma unroll
  for (int i = 0; i < 4; ++i)
#pragma unroll
    for (int j = 0; j < 4; ++j) acc[i][j] = zero;

  const char* XSb = (const char*)XS3h;
  const char* WBb = (const char*)WB;
  int lr = l >> 3;
  int lsw = ((l & 7) ^ lr) << 4;

#define STAGE(s_, b_)                                                              \
  {                                                                                \
    size_t bofs_ = (size_t)((s_) & 3) << 7;                                        \
    size_t aofs_ = ((s_) < 4) ? ((size_t)(s_) << 7)                                \
                              : (size_t)(512 + (((s_) - 4) << 7));                 \
    char* Ad_ = (char*)Asl + (b_) * 16384;                                         \
    char* Bd_ = (char*)Bsl + (b_) * 16384;                                         \
    _Pragma("unroll")                                                              \
    for (int q_ = 0; q_ < 4; ++q_) {                                               \
      int seg_ = wid * 32 + q_ * 8;                                                \
      GLOAD_LDS16(XSb + (size_t)(n0 + seg_ + lr) * 1536 + aofs_ + lsw,             \
                  Ad_ + seg_ * 128);                                               \
      GLOAD_LDS16(WBb + (size_t)(k0 + seg_ + lr) * 512 + bofs_ + lsw,              \
                  Bd_ + seg_ * 128);                                               \
    }                                                                              \
  }

  STAGE(0, 0);
  asm volatile("s_waitcnt vmcnt(0)" ::: "memory");
  __builtin_amdgcn_s_barrier();
  __builtin_amdgcn_sched_barrier(0);

  int buf = 0;
  for (int s = 0; s < 8; ++s) {
    if (s < 7) STAGE(s + 1, buf ^ 1);
    const ushort* Ab = &Asl[buf][0];
    const ushort* Bb = &Bsl[buf][0];
#pragma unroll
    for (int kk = 0; kk < 2; ++kk) {
      bf16x8 af[4], bg[4];
#pragma unroll
      for (int i = 0; i < 4; ++i) {
        int row = wr * 64 + i * 16 + c;
        int ch = (kk * 4 + hi) ^ (row & 7);
        af[i] = *(const bf16x8*)&Ab[row * 64 + ch * 8];
      }
#pragma unroll
      for (int j = 0; j < 4; ++j) {
        int row = wc * 64 + j * 16 + c;
        int ch = (kk * 4 + hi) ^ (row & 7);
        bg[j] = *(const bf16x8*)&Bb[row * 64 + ch * 8];
      }
#pragma unroll
      for (int i = 0; i < 4; ++i)
#pragma unroll
        for (int j = 0; j < 4; ++j)
          acc[i][j] = __builtin_amdgcn_mfma_f32_16x16x32_bf16(af[i], bg[j], acc[i][j], 0, 0, 0);
    }
    asm volatile("s_waitcnt vmcnt(0)" ::: "memory");
    __builtin_amdgcn_s_barrier();
    buf ^= 1;
  }
#undef STAGE

  // epilogue: nd + S store
#pragma unroll
  for (int i = 0; i < 4; ++i) {
#pragma unroll
    for (int r = 0; r < 4; ++r) {
      int nl = wr * 64 + i * 16 + hi * 4 + r;
      float xs = xsl[nl];
#pragma unroll
      for (int j = 0; j < 4; ++j) {
        int kl = wc * 64 + j * 16 + c;
        float nd = fmaf(2.f, acc[i][j][r], -(xs + wsl[kl]));
        S[(size_t)(n0 + nl) * 1024 + k0 + kl] = nd;
      }
    }
  }
}

// ---------------- row stats: max, 1/sum, top2(nd+g), entropy (S read-only) ----------------
__global__ __launch_bounds__(256) void k_rowstat(const float* __restrict__ S,
                                                 const float* __restrict__ Gh,
                                                 float* __restrict__ Mrowh,
                                                 float* __restrict__ Irowh,
                                                 float* __restrict__ benth,
                                                 int* __restrict__ t2igh) {
  __shared__ float went[4];
  int t = threadIdx.x;
  int l = t & 63, wv = t >> 6;
  int n = blockIdx.x * 4 + wv;
  const float* row = S + ((size_t)n << 10);
  const float* grow = Gh + ((size_t)n << 10);
  float v[16];
  float mx = -3.0e38f;
  float v1 = -3.0e38f, v2 = -3.0e38f;
  int i1 = 0x7fffffff, i2 = 0x7fffffff;
#pragma unroll
  for (int j = 0; j < 4; ++j) {
    float4 a = *(const float4*)&row[j * 256 + l * 4];
    float4 gg = *(const float4*)&grow[j * 256 + l * 4];
    float av[4] = {a.x, a.y, a.z, a.w};
    float gv[4] = {gg.x, gg.y, gg.z, gg.w};
#pragma unroll
    for (int q = 0; q < 4; ++q) {
      v[j * 4 + q] = av[q];
      mx = fmaxf(mx, av[q]);
      float sc = av[q] + gv[q];
      int kk = j * 256 + l * 4 + q;
      if (sc > v1 || (sc == v1 && kk < i1)) { v2 = v1; i2 = i1; v1 = sc; i1 = kk; }
      else if (sc > v2 || (sc == v2 && kk < i2)) { v2 = sc; i2 = kk; }
    }
  }
#pragma unroll
  for (int off = 1; off < 64; off <<= 1) {
    mx = fmaxf(mx, __shfl_xor(mx, off));
    float ov1 = __shfl_xor(v1, off), ov2 = __shfl_xor(v2, off);
    int oi1 = __shfl_xor(i1, off), oi2 = __shfl_xor(i2, off);
    bool fB = (ov1 > v1) || (ov1 == v1 && oi1 < i1);
    float nv1 = fB ? ov1 : v1; int ni1 = fB ? oi1 : i1;
    float ca = fB ? v1 : ov1;  int cia = fB ? i1 : oi1;
    float cb = fB ? ov2 : v2;  int cib = fB ? oi2 : i2;
    bool sB = (cb > ca) || (cb == ca && cib < cia);
    v1 = nv1; i1 = ni1;
    v2 = sB ? cb : ca; i2 = sB ? cib : cia;
  }
  float M = 2.f * mx;
  float e[16]; float ps = 0.f;
#pragma unroll
  for (int u = 0; u < 16; ++u) { e[u] = __expf(fmaf(2.f, v[u], -M)); ps += e[u]; }
  ps = wred_sum(ps);
  float inv = 1.f / ps;
  float ent = 0.f;
#pragma unroll
  for (int u = 0; u < 16; ++u) {
    float sfv = e[u] * inv;
    ent += sfv * __logf(fmaxf(sfv, 1e-8f));
  }
  ent = wred_sum(ent);
  if (l == 0) {
    t2igh[n * 2] = i1; t2igh[n * 2 + 1] = i2;
    Mrowh[n] = M; Irowh[n] = inv;
    went[wv] = ent;
  }
  __syncthreads();
  if (t == 0) benth[blockIdx.x] = went[0] + went[1] + went[2] + went[3];
}

// ---------------- soft recompute + bf16 transpose write: softT[k][nloc] ----------------
__global__ __launch_bounds__(512) void k_rowwrite(const float* __restrict__ S,
                                                  const float* __restrict__ Mrowh,
                                                  const float* __restrict__ Irowh,
                                                  ushort* __restrict__ sTp) {
  __shared__ ushort lds[64 * 65];
  __shared__ float Ml[64], Il[64];
  int t = threadIdx.x;
  int n0 = blockIdx.x * 64;
  if (t < 64) { Ml[t] = Mrowh[n0 + t]; Il[t] = Irowh[n0 + t]; }
  __syncthreads();
  for (int kt = 0; kt < 16; ++kt) {
    int k0 = kt * 64;
    int row = t >> 3, c8 = (t & 7) * 8;
    float M = Ml[row], inv = Il[row];
    const float* sp = &S[(size_t)(n0 + row) * 1024 + k0 + c8];
    float4 a = *(const float4*)sp;
    float4 b = *(const float4*)(sp + 4);
    float sv[8] = {a.x, a.y, a.z, a.w, b.x, b.y, b.z, b.w};
    ushort* d = &lds[row * 65 + c8];
#pragma unroll
    for (int j = 0; j < 8; ++j)
      d[j] = f2bf(__expf(fmaf(2.f, sv[j], -M)) * inv);
    __syncthreads();
    int krow = t >> 3, nc8 = (t & 7) * 8;
    uint* dst = (uint*)&sTp[(size_t)(k0 + krow) * NHALF + n0 + nc8];
#pragma unroll
    for (int j = 0; j < 4; ++j) {
      uint lo = lds[(nc8 + 2 * j) * 65 + krow];
      uint hh = lds[(nc8 + 2 * j + 1) * 65 + krow];
      dst[j] = lo | (hh << 16);
    }
    __syncthreads();
  }
}

// ---------------- exact argmax refinement ----------------
__global__ __launch_bounds__(256) void k_refine(const ushort* __restrict__ XS3,
                                                const float* __restrict__ w,
                                                const float* __restrict__ wsq,
                                                const float* __restrict__ xsq,
                                                const float* __restrict__ G,
                                                const int* __restrict__ t2ig,
                                                int* __restrict__ idxArr,
                                                float* __restrict__ hcnt) {
  int t = threadIdx.x;
  int l = t & 63, wv = t >> 6;
  int base = blockIdx.x * 64 + wv * 16;
  int d0 = l * 4;
  for (int rr = 0; rr < 16; ++rr) {
    int n = base + rr;
    const ushort* p = XS3 + (size_t)n * 768;
    union { uint2 q; ushort u[4]; } ha, ma, la;
    ha.q = *(const uint2*)&p[d0];
    ma.q = *(const uint2*)&p[256 + d0];
    la.q = *(const uint2*)&p[512 + d0];
    float xv[4];
#pragma unroll
    for (int q = 0; q < 4; ++q) xv[q] = bf2f(ha.u[q]) + bf2f(ma.u[q]) + bf2f(la.u[q]);
    float xs = xsq[n];
    int ia = t2ig[n * 2], ib = t2ig[n * 2 + 1];
    float sc[2];
    int ids[2] = {ia, ib};
#pragma unroll
    for (int cdd = 0; cdd < 2; ++cdd) {
      int id = ids[cdd];
      const float* wr = w + (size_t)id * DDIM;
      float4 wv4 = *(const float4*)&wr[d0];
      float d = xv[0] * wv4.x + xv[1] * wv4.y + xv[2] * wv4.z + xv[3] * wv4.w;
      d = wred_sum(d);
      sc[cdd] = fmaf(2.f, d, -xs) - wsq[id] + G[((size_t)n << 10) + id];
    }
    int win = (sc[1] > sc[0] || (sc[1] == sc[0] && ib < ia)) ? ib : ia;
    if (l == 0) {
      idxArr[n] = win;
      atomicAdd(&hcnt[win], 1.f);
    }
  }
}

// ---------------- quantized output ----------------
__global__ void k_quant(const float* __restrict__ w, const int* __restrict__ idxArr,
                        float* __restrict__ outQ) {
  int n = blockIdx.x * 256 + threadIdx.x;
  int b = n >> 10, m = n & 1023;
  int id = idxArr[n];
  const float* wr = w + (size_t)id * DDIM;
  float* o = outQ + (size_t)b * DDIM * 1024 + m;
#pragma unroll 4
  for (int d = 0; d < DDIM; ++d) o[(size_t)d * 1024] = wr[d];
}

// ---------------- GEMM2 (MFMA bf16): dw = soft^T x ; XCD-chunked swizzle ----------------
__global__ __launch_bounds__(512) void k_gemm2_mfma(const ushort* __restrict__ sT0,
                                                    const ushort* __restrict__ sT1,
                                                    const float* __restrict__ x,
                                                    float* __restrict__ P) {
  __shared__ __align__(16) ushort Abuf[256 * 72];
  __shared__ __align__(16) ushort Bbuf[128 * 72];
  int t = threadIdx.x;
  int h = blockIdx.x;                 // 0..255
  int xcd = h & 7, seq = h >> 3;      // 32 per XCD
  int ns = xcd * 4 + (seq >> 3);
  int ktdt = seq & 7;
  int kt = ktdt & 3, dt = ktdt >> 2;
  int k0 = kt * 256, d0 = dt * 128;
  int l = t & 63, wv = t >> 6;
  int wk = wv >> 1, wd = wv & 1;
  const ushort* Abase = (ns < 16) ? sT0 : sT1;
  size_t nloc0 = (size_t)(ns & 15) * 1024;
  f32x4 zero = {0.f, 0.f, 0.f, 0.f};
  f32x4 acc[4][4];
#pragma unroll
  for (int i = 0; i < 4; ++i)
#pragma unroll
    for (int j = 0; j < 4; ++j) acc[i][j] = zero;

  int colv = (t & 7) * 8;
  int rbase = t >> 3;
  for (int s = 0; s < 16; ++s) {
#pragma unroll
    for (int p = 0; p < 4; ++p) {
      int row = p * 64 + rbase;
      const uint* ap = (const uint*)(Abase + (size_t)(k0 + row) * NHALF + nloc0 + s * 64 + colv);
      uint4 v; v.x = ap[0]; v.y = ap[1]; v.z = ap[2]; v.w = ap[3];
      *(uint4*)&Abuf[row * 72 + colv] = v;
    }
#pragma unroll
    for (int p = 0; p < 2; ++p) {
      int row = p * 64 + rbase;
      const float* xp = &x[((size_t)ns * DDIM + d0 + row) * 1024 + s * 64 + colv];
      float4 a = *(const float4*)xp;
      float4 b = *(const float4*)(xp + 4);
      union { ushort u[8]; uint4 q; } pk;
      pk.u[0] = f2bf(a.x); pk.u[1] = f2bf(a.y); pk.u[2] = f2bf(a.z); pk.u[3] = f2bf(a.w);
      pk.u[4] = f2bf(b.x); pk.u[5] = f2bf(b.y); pk.u[6] = f2bf(b.z); pk.u[7] = f2bf(b.w);
      *(uint4*)&Bbuf[row * 72 + colv] = pk.q;
    }
    __syncthreads();
    bf16x8 af[4], bfr[4];
#pragma unroll
    for (int nb2 = 0; nb2 < 2; ++nb2) {
#pragma unroll
      for (int sub = 0; sub < 4; ++sub) {
        af[sub] = *(const bf16x8*)&Abuf[(wk * 64 + sub * 16 + (l & 15)) * 72 + nb2 * 32 + (l >> 4) * 8];
        bfr[sub] = *(const bf16x8*)&Bbuf[(wd * 64 + sub * 16 + (l & 15)) * 72 + nb2 * 32 + (l >> 4) * 8];
      }
#pragma unroll
      for (int i = 0; i < 4; ++i)
#pragma unroll
        for (int j = 0; j < 4; ++j)
          acc[i][j] = __builtin_amdgcn_mfma_f32_16x16x32_bf16(af[i], bfr[j], acc[i][j], 0, 0, 0);
    }
    __syncthreads();
  }
  float* Pb = P + (size_t)ns * (KCB * DDIM);
#pragma unroll
  for (int i = 0; i < 4; ++i)
#pragma unroll
    for (int j = 0; j < 4; ++j) {
#pragma unroll
      for (int r = 0; r < 4; ++r) {
        int k = k0 + wk * 64 + i * 16 + (l >> 4) * 4 + r;
        int d = d0 + wd * 64 + j * 16 + (l & 15);
        Pb[(size_t)k * DDIM + d] = acc[i][j][r];
      }
    }
}

// ---------------- colsum over two softT panels ----------------
__global__ void k_colsum2(const ushort* __restrict__ sT0, const ushort* __restrict__ sT1,
                          float* __restrict__ colsum) {
  int k = blockIdx.x;
  int t = threadIdx.x;
  const uint* r0 = (const uint*)(sT0 + (size_t)k * NHALF);
  const uint* r1 = (const uint*)(sT1 + (size_t)k * NHALF);
  float s = 0.f;
#pragma unroll
  for (int cc = 0; cc < 8; ++cc) {
#pragma unroll
    for (int q = 0; q < 4; ++q) {
      uint a = r0[cc * 1024 + t * 4 + q];
      uint b = r1[cc * 1024 + t * 4 + q];
      s += bf2f((ushort)(a & 0xffffu)) + bf2f((ushort)(a >> 16));
      s += bf2f((ushort)(b & 0xffffu)) + bf2f((ushort)(b >> 16));
    }
  }
  s = wred_sum(s);
  __shared__ float ws4[4];
  if ((t & 63) == 0) ws4[t >> 6] = s;
  __syncthreads();
  if (t == 0) colsum[k] = ws4[0] + ws4[1] + ws4[2] + ws4[3];
}

// ---------------- finalize scalars, new_count ----------------
__global__ void k_final1(const float* __restrict__ ema_count, const float* __restrict__ colsum,
                         const float* __restrict__ hcnt, const float* __restrict__ bent,
                         float* __restrict__ ncnt, float* __restrict__ out) {
  __shared__ float red[1024];
  int t = threadIdx.x;
  const float onem = 1.0f - 0.99f;
  float nc = ema_count[t] * 0.99f + colsum[t] * onem;
  nc = (nc + 1e-5f) / (32768.0f + 1024.0f * 1e-5f) * 32768.0f;
  out[O_NCNT + t] = nc;
  ncnt[t] = nc;
  float s = 0.f;
  for (int i = t; i < 8192; i += 1024) s += bent[i];
  red[t] = s;
  __syncthreads();
  for (int off = 512; off > 0; off >>= 1) { if (t < off) red[t] += red[t + off]; __syncthreads(); }
  if (t == 0) out[O_LOSS] = 0.25f * (red[0] / 32768.0f);
  __syncthreads();
  float avg = hcnt[t] * (1.0f / 32768.0f);
  red[t] = avg * logf(avg + 1e-10f);
  __syncthreads();
  for (int off = 512; off > 0; off >>= 1) { if (t < off) red[t] += red[t + off]; __syncthreads(); }
  if (t == 0) out[O_PERP] = expf(-red[0]);
}

// ---------------- reduce dw partials + new_ema_weight & new_embedding ----------------
__global__ void k_reduce_final2(const float* __restrict__ P, const float* __restrict__ ema_w,
                                const float* __restrict__ ncnt, float* __restrict__ outEW,
                                float* __restrict__ outEMB) {
  int i = blockIdx.x * 256 + threadIdx.x;
  float s = 0.f;
#pragma unroll
  for (int ns = 0; ns < 32; ++ns) s += P[(size_t)ns * (KCB * DDIM) + i];
  float ew = ema_w[i] * 0.99f + s * 0.01f;
  outEW[i] = ew;
  outEMB[i] = ew / ncnt[i >> 8];
}

// ---------------- one-hot encodings (overwrites E scratch, last) ----------------
__global__ void k_onehot(const int* __restrict__ idxArr, float* __restrict__ E) {
  int gid = blockIdx.x * 256 + threadIdx.x;
  int n = gid >> 8;
  int k4 = (gid & 255) * 4;
  int id = idxArr[n];
  float2* E2 = (float2*)E;
  size_t base = ((size_t)n * KCB + k4) >> 1;
  float2 vA = {(float)(k4 == id), (float)(k4 + 1 == id)};
  float2 vB = {(float)(k4 + 2 == id), (float)(k4 + 3 == id)};
  E2[base] = vA;
  E2[base + 1] = vB;
}

extern "C" void kernel_launch(void* const* d_in, const int* in_sizes, int n_in,
                              void* d_out, int out_size, void* d_ws, size_t ws_size,
                              hipStream_t stream) {
  const float* x = (const float*)d_in[0];
  const float* w = (const float*)d_in[1];
  const float* ema_count = (const float*)d_in[2];
  const float* ema_w = (const float*)d_in[3];
  const float* g = (const float*)d_in[4];
  float* out = (float*)d_out;
  float* ws = (float*)d_ws;

  float* wsq    = ws + W_WSQ;
  float* xsq    = ws + W_XSQ;
  int*   idxArr = (int*)(ws + W_IDX);
  float* colsum = ws + W_COL;
  float* hcnt   = ws + W_HCNT;
  float* bent   = ws + W_BENT;
  float* ncnt   = ws + W_NCNT;
  int*   top2i  = (int*)(ws + W_T2I);
  ushort* WB    = (ushort*)(ws + W_WB);
  float* Mrow   = ws + W_MROW;
  float* Irow   = ws + W_IROW;

  float* outQ = out + O_Q;
  float* outE = out + O_ENC;

  ushort* XS3    = (ushort*)(outE + E_XS3);     // 16B-aligned
  float*  Sslot  = outE + E_S;                  // 16B-aligned
  ushort* softT1 = (ushort*)(outE + E_XS3);     // overwrites XS3 after refine
  ushort* softT0 = (ushort*)outQ;               // Q region (4B-aligned: uint ops only)

  k_init<<<4, 256, 0, stream>>>(hcnt);
  k_wsplit<<<256, 256, 0, stream>>>(w, wsq, WB);
  k_xsplit<<<1024, 256, 0, stream>>>(x, XS3, xsq);
  // ---- half 0 (rows 0..16383) ----
  k_gemm1t<<<1024, 256, 0, stream>>>(XS3, WB, wsq, xsq, Sslot);
  k_rowstat<<<4096, 256, 0, stream>>>(Sslot, g, Mrow, Irow, bent, top2i);
  k_rowwrite<<<256, 512, 0, stream>>>(Sslot, Mrow, Irow, softT0);
  // ---- half 1 (rows 16384..32767) ----
  k_gemm1t<<<1024, 256, 0, stream>>>(XS3 + (size_t)NHALF * 768, WB,
                                     wsq, xsq + NHALF, Sslot);
  k_rowstat<<<4096, 256, 0, stream>>>(Sslot, g + (size_t)NHALF * 1024,
                                      Mrow + NHALF, Irow + NHALF,
                                      bent + 4096, top2i + NHALF * 2);
  k_refine<<<512, 256, 0, stream>>>(XS3, w, wsq, xsq, g, top2i, idxArr, hcnt);
  k_rowwrite<<<256, 512, 0, stream>>>(Sslot, Mrow + NHALF, Irow + NHALF, softT1);
  k_colsum2<<<1024, 256, 0, stream>>>(softT0, softT1, colsum);
  k_gemm2_mfma<<<256, 512, 0, stream>>>(softT0, softT1, x, Sslot);  // P -> Sslot head
  k_final1<<<1, 1024, 0, stream>>>(ema_count, colsum, hcnt, bent, ncnt, out);
  k_reduce_final2<<<1024, 256, 0, stream>>>(Sslot, ema_w, ncnt, out + O_EMAW, out + O_EMB);
  k_quant<<<128, 256, 0, stream>>>(w, idxArr, outQ);       // overwrites softT0
  k_onehot<<<32768, 256, 0, stream>>>(idxArr, outE);       // overwrites all E scratch
}